// Round 1
// baseline (2328.932 us; speedup 1.0000x reference)
//
#include <hip/hip_runtime.h>
#include <cstdint>
#include <cstddef>

#pragma clang fp contract(off)

#define BATCH    8
#define NANCH    261888
#define PRE_NMS  6000
#define PROP     1000
#define SORTN    8192
#define NSLOT    6144          /* 6 * 1024 */
#define SCORE_THRES_BITS 0x3F000000u   /* bits of 0.5f */
#define IOU_T    0.7f
#define EPS_F    1e-8f

typedef unsigned long long ull;

// Wave-aggregated histogram add: up to 2 leader rounds (handles the heavily
// clustered exponent bins of softmax scores), then plain atomics for leftovers.
__device__ __forceinline__ void hist_add(unsigned int* hist, unsigned int bin, bool valid) {
    const int lane = threadIdx.x & 63;
    ull todo = __ballot(valid ? 1 : 0);
    #pragma unroll
    for (int it = 0; it < 2; ++it) {
        if (!todo) return;                       // uniform
        int leader = __ffsll(todo) - 1;
        unsigned int lbin = __shfl(bin, leader);
        ull grp = __ballot((valid && (bin == lbin)) ? 1 : 0);
        if (lane == leader) atomicAdd(&hist[lbin], (unsigned int)__popcll(grp));
        todo &= ~grp;
    }
    if ((todo >> lane) & 1ull) atomicAdd(&hist[bin], 1u);
}

template<int USE_WS>
__global__ __launch_bounds__(1024)
void proposal_kernel(const float* __restrict__ rpn_probs,
                     const float* __restrict__ rpn_bbox,
                     const float* __restrict__ anchors,
                     float* __restrict__ out,
                     float* __restrict__ scores_ws)
{
    const int b    = blockIdx.x;
    const int t    = threadIdx.x;
    const int lane = t & 63;
    const int wv   = t >> 6;

    const float2* __restrict__ probs2 = reinterpret_cast<const float2*>(rpn_probs + (size_t)b * NANCH * 2);
    const float4* __restrict__ bbox4  = reinterpret_cast<const float4*>(rpn_bbox  + (size_t)b * NANCH * 4);
    const float4* __restrict__ anc4   = reinterpret_cast<const float4*>(anchors   + (size_t)b * NANCH * 4);
    float* __restrict__ outb = out + (size_t)b * PROP * 4;
    float* __restrict__ swb  = USE_WS ? (scores_ws + (size_t)b * NANCH) : nullptr;

    // 96 KB region: sel u64[8192] (select/sort phase) aliased with boxes float4[6144] (NMS phase)
    __shared__ __align__(16) char s_big[NSLOT * 16];
    __shared__ ull          s_alive[96];
    __shared__ unsigned int s_hist[256];
    __shared__ unsigned int s_pref;
    __shared__ unsigned int s_targ;
    __shared__ unsigned int s_cnt;

    ull*    sel   = reinterpret_cast<ull*>(s_big);
    float4* boxes = reinterpret_cast<float4*>(s_big);

    const int ITER = (NANCH + 1023) >> 10;   // 256

    if (t == 0) { s_pref = 0u; s_targ = PRE_NMS; s_cnt = 0u; }

    // ---------- phase 1: exact radix-select of the 6000th largest score ----------
    for (int p = 0; p < 4; ++p) {
        if (t < 256) s_hist[t] = 0u;
        __syncthreads();
        const unsigned int pref  = s_pref;
        const int          shift = 8 * (3 - p);
        const unsigned int pmask = (p == 0) ? 0u : (0xFFFFFFFFu << (shift + 8));
        for (int i = 0; i < ITER; ++i) {
            int  n     = (i << 10) + t;
            bool valid = (n < NANCH);
            unsigned int key = 0u;
            if (valid) {
                float sc;
                if (USE_WS) {
                    if (p == 0) { sc = probs2[n].y; swb[n] = sc; }
                    else        { sc = swb[n]; }
                } else {
                    sc = probs2[n].y;
                }
                key = __float_as_uint(sc);
            }
            bool match = valid && ((key & pmask) == (pref & pmask));
            hist_add(s_hist, (key >> shift) & 0xFFu, match);
        }
        __syncthreads();
        if (t == 0) {
            unsigned int target = s_targ;
            unsigned int acc = 0u;
            int v = 255;
            for (; v >= 0; --v) {
                unsigned int h = s_hist[v];
                if (acc + h >= target) break;
                acc += h;
            }
            if (v < 0) v = 0;  // unreachable; safety
            s_pref = pref | ((unsigned int)v << shift);
            s_targ = target - acc;
        }
        __syncthreads();
    }

    const unsigned int T = s_pref;   // exact 32-bit key of the 6000th largest score
    __syncthreads();

    // ---------- phase 2: compact all keys >= T (count C in [6000, ~6000+dups]) ----------
    for (int i = 0; i < ITER; ++i) {
        int  n     = (i << 10) + t;
        bool valid = (n < NANCH);
        unsigned int key = 0u;
        if (valid) {
            float sc = USE_WS ? swb[n] : probs2[n].y;
            key = __float_as_uint(sc);
        }
        bool selp = valid && (key >= T);
        ull  m    = __ballot(selp ? 1 : 0);
        if (m) {
            int leader = __ffsll(m) - 1;
            unsigned int base = 0u;
            if (lane == leader) base = atomicAdd(&s_cnt, (unsigned int)__popcll(m));
            base = __shfl(base, leader);
            if (selp) {
                unsigned int off = base + (unsigned int)__popcll(m & ((1ull << lane) - 1ull));
                if (off < SORTN) sel[off] = ((ull)(~key) << 32) | (ull)(unsigned int)n;
            }
        }
    }
    __syncthreads();
    const unsigned int C = s_cnt;
    for (int s = (int)C + t; s < SORTN; s += 1024) sel[s] = ~0ull;
    __syncthreads();

    // ---------- phase 3: bitonic sort ascending by (~score_bits, index) ----------
    for (unsigned int k = 2; k <= SORTN; k <<= 1) {
        for (unsigned int j = k >> 1; j > 0; j >>= 1) {
            #pragma unroll
            for (int r = 0; r < SORTN / 1024; ++r) {
                int i = (r << 10) + t;
                int l = i ^ (int)j;
                if (l > i) {
                    ull a  = sel[i];
                    ull bq = sel[l];
                    bool up = ((i & (int)k) == 0);
                    if ((a > bq) == up) { sel[i] = bq; sel[l] = a; }
                }
            }
            __syncthreads();
        }
    }

    // ---------- phase 4: stage sorted keys, decode boxes (registers + LDS) ----------
    ull ss[6];
    #pragma unroll
    for (int e = 0; e < 6; ++e) ss[e] = sel[(e << 10) + t];
    __syncthreads();   // sel reads done before boxes overwrite the region

    float4 rbox[6];
    float  rarea[6];
    #pragma unroll
    for (int e = 0; e < 6; ++e) {
        int s = (e << 10) + t;
        float4 bx = make_float4(0.f, 0.f, 0.f, 0.f);
        bool ok = false;
        if (s < PRE_NMS) {
            unsigned int key = ~(unsigned int)(ss[e] >> 32);
            unsigned int n   = (unsigned int)(ss[e] & 0xFFFFFFFFull);
            float4 a = anc4[n];
            float4 d = bbox4[n];
            float dy = d.x * 0.1f, dx = d.y * 0.1f, dh = d.z * 0.2f, dw = d.w * 0.2f;
            float h  = a.z - a.x;
            float w  = a.w - a.y;
            float cy = a.x + 0.5f * h;
            float cx = a.y + 0.5f * w;
            cy = cy + dy * h;
            cx = cx + dx * w;
            h  = h * expf(dh);
            w  = w * expf(dw);
            float y1 = cy - 0.5f * h;
            float x1 = cx - 0.5f * w;
            float y2 = y1 + h;
            float x2 = x1 + w;
            y1 = fminf(fmaxf(y1, 0.f), 1.f);
            x1 = fminf(fmaxf(x1, 0.f), 1.f);
            y2 = fminf(fmaxf(y2, 0.f), 1.f);
            x2 = fminf(fmaxf(x2, 0.f), 1.f);
            bx = make_float4(y1, x1, y2, x2);
            ok = (key >= SCORE_THRES_BITS);
        }
        rbox[e]  = bx;
        rarea[e] = (bx.z - bx.x) * (bx.w - bx.y);
        boxes[s] = bx;
        ull am = __ballot(ok ? 1 : 0);
        if (lane == 0) s_alive[wv + (e << 4)] = am;   // word = wv + 16e, unique per (wave,e)
    }

    // ---------- phase 5: greedy NMS (sequential over picks) ----------
    int emitted = 0;
    for (;;) {
        __syncthreads();   // (A) alive updates from previous iteration visible
        if (emitted == PROP) break;
        // each wave redundantly finds the first alive slot (no broadcast needed)
        ull w0 = s_alive[lane];
        ull w1 = (lane < 32) ? s_alive[64 + lane] : 0ull;
        ull nz0 = __ballot(w0 != 0ull ? 1 : 0);
        ull nz1 = __ballot(w1 != 0ull ? 1 : 0);
        int pick = -1;
        if (nz0) {
            int wd = __ffsll(nz0) - 1;
            ull wval = __shfl(w0, wd);
            pick = (wd << 6) + __ffsll(wval) - 1;
        } else if (nz1) {
            int wd = __ffsll(nz1) - 1;
            ull wval = __shfl(w1, wd);
            pick = ((wd + 64) << 6) + __ffsll(wval) - 1;
        }
        if (pick < 0) break;
        __syncthreads();   // (B) all waves finished reading alive before updates

        if (t < 4) outb[(emitted << 2) + t] = reinterpret_cast<const float*>(s_big)[(pick << 2) + t];

        float4 p = boxes[pick];   // LDS broadcast (uniform address)
        float parea = (p.z - p.x) * (p.w - p.y);
        #pragma unroll
        for (int e = 0; e < 6; ++e) {
            float4 bb  = rbox[e];
            float yy1 = fmaxf(p.x, bb.x);
            float xx1 = fmaxf(p.y, bb.y);
            float yy2 = fminf(p.z, bb.z);
            float xx2 = fminf(p.w, bb.w);
            float ih  = fmaxf(yy2 - yy1, 0.f);
            float iw  = fmaxf(xx2 - xx1, 0.f);
            float inter = ih * iw;
            float denom = ((parea + rarea[e]) - inter) + EPS_F;
            float iou   = inter / denom;          // IEEE f32 divide, matches np
            bool  sup   = (iou >= IOU_T);
            ull m = __ballot(sup ? 1 : 0);
            int word = wv + (e << 4);
            if (word == (pick >> 6)) m |= (1ull << (pick & 63));  // explicit self-clear (zero-area safety)
            if (lane == 0) s_alive[word] &= ~m;
        }
        ++emitted;
    }

    // zero-fill remaining rows (d_out is poisoned before every launch)
    for (int i = (emitted << 2) + t; i < PROP * 4; i += 1024) outb[i] = 0.f;
}

extern "C" void kernel_launch(void* const* d_in, const int* in_sizes, int n_in,
                              void* d_out, int out_size, void* d_ws, size_t ws_size,
                              hipStream_t stream) {
    const float* rpn_probs = (const float*)d_in[0];
    const float* rpn_bbox  = (const float*)d_in[1];
    const float* anchors   = (const float*)d_in[2];
    float* out = (float*)d_out;

    const size_t need = (size_t)BATCH * NANCH * sizeof(float);
    if (d_ws != nullptr && ws_size >= need) {
        hipLaunchKernelGGL((proposal_kernel<1>), dim3(BATCH), dim3(1024), 0, stream,
                           rpn_probs, rpn_bbox, anchors, out, (float*)d_ws);
    } else {
        hipLaunchKernelGGL((proposal_kernel<0>), dim3(BATCH), dim3(1024), 0, stream,
                           rpn_probs, rpn_bbox, anchors, out, (float*)nullptr);
    }
}

// Round 2
// 1620.022 us; speedup vs baseline: 1.4376x; 1.4376x over previous
//
#include <hip/hip_runtime.h>
#include <cstdint>
#include <cstddef>

#pragma clang fp contract(off)

#define BATCH    8
#define NANCH    261888
#define PRE_NMS  6000
#define PROP     1000
#define SORTN    8192
#define NSLOT    6144          /* 6 * 1024 */
#define MROW     96            /* u64 words per suppression row (94 used + 2 pad) */
#define SCORE_THRES_BITS 0x3F000000u   /* bits of 0.5f */
#define IOU_T    0.7f
#define EPS_F    1e-8f
/* midpoint between pred(0.7f) and 0.7f = 23488101 * 2^-25, exact in double.
   RN(inter/denom) >= 0.7f  <=>  inter > M_D * denom  (exact: 25b x 24b product). */
#define M_D      0.6999999582767486572265625

typedef unsigned long long ull;

// Wave-aggregated histogram add: 3 leader rounds (softmax scores cluster in few
// exponent bins), then plain atomics for leftovers.
__device__ __forceinline__ void hist_add(unsigned int* hist, unsigned int bin, bool valid) {
    const int lane = threadIdx.x & 63;
    ull todo = __ballot(valid ? 1 : 0);
    #pragma unroll
    for (int it = 0; it < 3; ++it) {
        if (!todo) return;                       // uniform
        int leader = __ffsll(todo) - 1;
        unsigned int lbin = __shfl(bin, leader);
        ull grp = __ballot((valid && (bin == lbin)) ? 1 : 0);
        if (lane == leader) atomicAdd(&hist[lbin], (unsigned int)__popcll(grp));
        todo &= ~grp;
    }
    if ((todo >> lane) & 1ull) atomicAdd(&hist[bin], 1u);
}

// ---------------------------------------------------------------------------
// Kernel 1: per-batch exact top-6000 select + sort + box decode.
// Writes sorted clipped boxes (6144 float4/batch) and alive bitmask (96 u64).
// ---------------------------------------------------------------------------
__global__ __launch_bounds__(1024)
void select_kernel(const float* __restrict__ rpn_probs,
                   const float* __restrict__ rpn_bbox,
                   const float* __restrict__ anchors,
                   float4* __restrict__ boxes_ws,
                   ull* __restrict__ alive_ws)
{
    const int b    = blockIdx.x;
    const int t    = threadIdx.x;
    const int lane = t & 63;
    const int wv   = t >> 6;

    const float2* __restrict__ probs2 = reinterpret_cast<const float2*>(rpn_probs + (size_t)b * NANCH * 2);
    const float4* __restrict__ bbox4  = reinterpret_cast<const float4*>(rpn_bbox  + (size_t)b * NANCH * 4);
    const float4* __restrict__ anc4   = reinterpret_cast<const float4*>(anchors   + (size_t)b * NANCH * 4);

    __shared__ ull          sel[SORTN];     // 64 KB
    __shared__ unsigned int s_hist[256];
    __shared__ unsigned int s_pref;
    __shared__ unsigned int s_targ;
    __shared__ unsigned int s_cnt;

    const int ITER = (NANCH + 1023) >> 10;   // 256

    if (t == 0) { s_pref = 0u; s_targ = PRE_NMS; s_cnt = 0u; }

    // ---------- phase 1: exact radix-select of the 6000th largest score ----------
    for (int p = 0; p < 4; ++p) {
        if (t < 256) s_hist[t] = 0u;
        __syncthreads();
        const unsigned int pref  = s_pref;
        const int          shift = 8 * (3 - p);
        const unsigned int pmask = (p == 0) ? 0u : (0xFFFFFFFFu << (shift + 8));
        for (int i = 0; i < ITER; ++i) {
            int  n     = (i << 10) + t;
            bool valid = (n < NANCH);
            unsigned int key = 0u;
            if (valid) key = __float_as_uint(probs2[n].y);
            bool match = valid && ((key & pmask) == (pref & pmask));
            hist_add(s_hist, (key >> shift) & 0xFFu, match);
        }
        __syncthreads();
        if (t == 0) {
            unsigned int target = s_targ;
            unsigned int acc = 0u;
            int v = 255;
            for (; v >= 0; --v) {
                unsigned int h = s_hist[v];
                if (acc + h >= target) break;
                acc += h;
            }
            if (v < 0) v = 0;
            s_pref = pref | ((unsigned int)v << shift);
            s_targ = target - acc;
        }
        __syncthreads();
    }

    const unsigned int T = s_pref;
    __syncthreads();

    // ---------- phase 2: compact all keys >= T ----------
    for (int i = 0; i < ITER; ++i) {
        int  n     = (i << 10) + t;
        bool valid = (n < NANCH);
        unsigned int key = 0u;
        if (valid) key = __float_as_uint(probs2[n].y);
        bool selp = valid && (key >= T);
        ull  m    = __ballot(selp ? 1 : 0);
        if (m) {
            int leader = __ffsll(m) - 1;
            unsigned int base = 0u;
            if (lane == leader) base = atomicAdd(&s_cnt, (unsigned int)__popcll(m));
            base = __shfl(base, leader);
            if (selp) {
                unsigned int off = base + (unsigned int)__popcll(m & ((1ull << lane) - 1ull));
                if (off < SORTN) sel[off] = ((ull)(~key) << 32) | (ull)(unsigned int)n;
            }
        }
    }
    __syncthreads();
    const unsigned int C = s_cnt;
    for (int s = (int)C + t; s < SORTN; s += 1024) sel[s] = ~0ull;
    __syncthreads();

    // ---------- phase 3: bitonic sort ascending by (~score_bits, index) ----------
    for (unsigned int k = 2; k <= SORTN; k <<= 1) {
        for (unsigned int j = k >> 1; j > 0; j >>= 1) {
            #pragma unroll
            for (int r = 0; r < SORTN / 1024; ++r) {
                int i = (r << 10) + t;
                int l = i ^ (int)j;
                if (l > i) {
                    ull a  = sel[i];
                    ull bq = sel[l];
                    bool up = ((i & (int)k) == 0);
                    if ((a > bq) == up) { sel[i] = bq; sel[l] = a; }
                }
            }
            __syncthreads();
        }
    }

    // ---------- phase 4: decode boxes, write boxes + alive words to ws ----------
    #pragma unroll
    for (int e = 0; e < 6; ++e) {
        int s = (e << 10) + t;
        float4 bx = make_float4(0.f, 0.f, 0.f, 0.f);
        bool ok = false;
        if (s < PRE_NMS) {
            ull ss = sel[s];
            unsigned int key = ~(unsigned int)(ss >> 32);
            unsigned int n   = (unsigned int)(ss & 0xFFFFFFFFull);
            float4 a = anc4[n];
            float4 d = bbox4[n];
            float dy = d.x * 0.1f, dx = d.y * 0.1f, dh = d.z * 0.2f, dw = d.w * 0.2f;
            float h  = a.z - a.x;
            float w  = a.w - a.y;
            float cy = a.x + 0.5f * h;
            float cx = a.y + 0.5f * w;
            cy = cy + dy * h;
            cx = cx + dx * w;
            h  = h * expf(dh);
            w  = w * expf(dw);
            float y1 = cy - 0.5f * h;
            float x1 = cx - 0.5f * w;
            float y2 = y1 + h;
            float x2 = x1 + w;
            y1 = fminf(fmaxf(y1, 0.f), 1.f);
            x1 = fminf(fmaxf(x1, 0.f), 1.f);
            y2 = fminf(fmaxf(y2, 0.f), 1.f);
            x2 = fminf(fmaxf(x2, 0.f), 1.f);
            bx = make_float4(y1, x1, y2, x2);
            ok = (key >= SCORE_THRES_BITS);
        }
        boxes_ws[(size_t)b * NSLOT + s] = bx;
        ull am = __ballot(ok ? 1 : 0);
        if (lane == 0) alive_ws[(size_t)b * MROW + wv + (e << 4)] = am;  // word = 16e+wv, slot = 64*word+lane
    }
}

// ---------------------------------------------------------------------------
// Kernel 2: suppression bit-matrix. Row r, bit j set iff j>r and IoU(r,j)>=0.7
// (exact predicate). Row stride MROW u64; words < r/64 and 94,95 zeroed.
// grid = (375, BATCH), block = 1024 (16 waves -> 16 rows/block).
// ---------------------------------------------------------------------------
__global__ __launch_bounds__(1024)
void iou_matrix_kernel(const float4* __restrict__ boxes_ws,
                       ull* __restrict__ mat)
{
    __shared__ float4 sbox[NSLOT];   // 96 KB
    const int b    = blockIdx.y;
    const int t    = threadIdx.x;
    const int lane = t & 63;
    const int wv   = t >> 6;

    const float4* bws = boxes_ws + (size_t)b * NSLOT;
    #pragma unroll
    for (int i = 0; i < 6; ++i) sbox[(i << 10) + t] = bws[(i << 10) + t];
    __syncthreads();

    const int r = (blockIdx.x << 4) + wv;
    if (r >= PRE_NMS) return;

    float4 p = sbox[r];                       // uniform -> LDS broadcast
    float pa = (p.z - p.x) * (p.w - p.y);
    ull* row = mat + ((size_t)b * PRE_NMS + r) * MROW;

    const int k0 = r >> 6;
    for (int w = lane; w < k0; w += 64) row[w] = 0;
    if (lane < 2) row[94 + lane] = 0;

    for (int k = k0; k < 94; ++k) {
        int c = (k << 6) + lane;              // c < 6016 <= NSLOT
        float4 q = sbox[c];
        float qa  = (q.z - q.x) * (q.w - q.y);
        float yy1 = fmaxf(p.x, q.x);
        float xx1 = fmaxf(p.y, q.y);
        float yy2 = fminf(p.z, q.z);
        float xx2 = fminf(p.w, q.w);
        float inter = fmaxf(yy2 - yy1, 0.f) * fmaxf(xx2 - xx1, 0.f);
        float denom = ((pa + qa) - inter) + EPS_F;
        bool sup = ((double)inter > M_D * (double)denom) && (c > r);
        ull m = __ballot(sup ? 1 : 0);
        if (lane == 0) row[k] = m;
    }
}

// ---------------------------------------------------------------------------
// Kernel 3: single-wave greedy scan per batch, group-of-8 speculative rows.
// grid = BATCH, block = 64.
// ---------------------------------------------------------------------------
__global__ __launch_bounds__(64)
void nms_scan_kernel(const float4* __restrict__ boxes_ws,
                     const ull* __restrict__ alive_ws,
                     const ull* __restrict__ mat,
                     float* __restrict__ out)
{
    const int b    = blockIdx.x;
    const int lane = threadIdx.x;

    __shared__ int picks[PROP];

    // alive: lane j holds words 2j, 2j+1 (j < 48); words 94,95 are zero.
    ull ax = 0, ay = 0;
    if (lane < 48) {
        const ull* aw = alive_ws + (size_t)b * MROW + 2 * lane;
        ax = aw[0]; ay = aw[1];
    }

    const ull* mb = mat + (size_t)b * PRE_NMS * MROW;
    int emitted = 0;

    for (;;) {
        // gather up to 8 leading alive candidates (uniform values)
        int cand[8];
        int ng = 0;
        ull tx = ax, ty = ay;
        while (ng < 8) {
            ull nz = __ballot((tx | ty) != 0ull ? 1 : 0);
            if (!nz) break;
            int owner = __ffsll(nz) - 1;
            ull wx = __shfl(tx, owner);
            ull wy = __shfl(ty, owner);
            int c;
            if (wx) c = (owner << 7) + (__ffsll(wx) - 1);
            else    c = (owner << 7) + 64 + (__ffsll(wy) - 1);
            cand[ng++] = c;
            if (lane == owner) {
                if (wx) tx &= tx - 1ull; else ty &= ty - 1ull;
            }
        }
        if (ng == 0) break;

        // issue all row loads together (latency overlap)
        ull rx[8], ry[8];
        #pragma unroll
        for (int g = 0; g < 8; ++g) {
            rx[g] = 0; ry[g] = 0;
            if (g < ng && lane < 48) {
                const ull* rp = mb + (size_t)cand[g] * MROW + 2 * lane;
                ulonglong2 v = *reinterpret_cast<const ulonglong2*>(rp);
                rx[g] = v.x; ry[g] = v.y;
            }
        }

        // resolve picks serially in-register
        ull remx = 0, remy = 0, clrx = 0, clry = 0;
        for (int g = 0; g < ng; ++g) {
            int c = cand[g];
            int owner = c >> 7;
            ull wx = __shfl(remx, owner);
            ull wy = __shfl(remy, owner);
            ull w  = (c & 64) ? wy : wx;
            bool dead = (w >> (c & 63)) & 1ull;
            if (!dead) {
                if (lane == 0) picks[emitted] = c;
                ++emitted;
                remx |= rx[g]; remy |= ry[g];
                int cw = c >> 6;
                if (lane == (cw >> 1)) {
                    if (cw & 1) clry |= 1ull << (c & 63);
                    else        clrx |= 1ull << (c & 63);
                }
                if (emitted == PROP) break;
            }
        }
        ax &= ~(remx | clrx);
        ay &= ~(remy | clry);
        if (emitted == PROP) break;
    }

    __syncthreads();   // LDS picks visible (single wave; also orders lgkmcnt)

    const float4* bws = boxes_ws + (size_t)b * NSLOT;
    float4* ob = reinterpret_cast<float4*>(out + (size_t)b * PROP * 4);
    for (int i = lane; i < PROP; i += 64) {
        float4 v = make_float4(0.f, 0.f, 0.f, 0.f);
        if (i < emitted) v = bws[picks[i]];
        ob[i] = v;
    }
}

// ---------------------------------------------------------------------------
// Fallback: round-1 monolithic kernel (used if ws too small). Verified exact.
// ---------------------------------------------------------------------------
__global__ __launch_bounds__(1024)
void proposal_fallback(const float* __restrict__ rpn_probs,
                       const float* __restrict__ rpn_bbox,
                       const float* __restrict__ anchors,
                       float* __restrict__ out)
{
    const int b    = blockIdx.x;
    const int t    = threadIdx.x;
    const int lane = t & 63;
    const int wv   = t >> 6;

    const float2* __restrict__ probs2 = reinterpret_cast<const float2*>(rpn_probs + (size_t)b * NANCH * 2);
    const float4* __restrict__ bbox4  = reinterpret_cast<const float4*>(rpn_bbox  + (size_t)b * NANCH * 4);
    const float4* __restrict__ anc4   = reinterpret_cast<const float4*>(anchors   + (size_t)b * NANCH * 4);
    float* __restrict__ outb = out + (size_t)b * PROP * 4;

    __shared__ __align__(16) char s_big[NSLOT * 16];
    __shared__ ull          s_alive[96];
    __shared__ unsigned int s_hist[256];
    __shared__ unsigned int s_pref;
    __shared__ unsigned int s_targ;
    __shared__ unsigned int s_cnt;

    ull*    sel   = reinterpret_cast<ull*>(s_big);
    float4* boxes = reinterpret_cast<float4*>(s_big);

    const int ITER = (NANCH + 1023) >> 10;

    if (t == 0) { s_pref = 0u; s_targ = PRE_NMS; s_cnt = 0u; }

    for (int p = 0; p < 4; ++p) {
        if (t < 256) s_hist[t] = 0u;
        __syncthreads();
        const unsigned int pref  = s_pref;
        const int          shift = 8 * (3 - p);
        const unsigned int pmask = (p == 0) ? 0u : (0xFFFFFFFFu << (shift + 8));
        for (int i = 0; i < ITER; ++i) {
            int  n     = (i << 10) + t;
            bool valid = (n < NANCH);
            unsigned int key = 0u;
            if (valid) key = __float_as_uint(probs2[n].y);
            bool match = valid && ((key & pmask) == (pref & pmask));
            hist_add(s_hist, (key >> shift) & 0xFFu, match);
        }
        __syncthreads();
        if (t == 0) {
            unsigned int target = s_targ;
            unsigned int acc = 0u;
            int v = 255;
            for (; v >= 0; --v) {
                unsigned int h = s_hist[v];
                if (acc + h >= target) break;
                acc += h;
            }
            if (v < 0) v = 0;
            s_pref = pref | ((unsigned int)v << shift);
            s_targ = target - acc;
        }
        __syncthreads();
    }

    const unsigned int T = s_pref;
    __syncthreads();

    for (int i = 0; i < ITER; ++i) {
        int  n     = (i << 10) + t;
        bool valid = (n < NANCH);
        unsigned int key = 0u;
        if (valid) key = __float_as_uint(probs2[n].y);
        bool selp = valid && (key >= T);
        ull  m    = __ballot(selp ? 1 : 0);
        if (m) {
            int leader = __ffsll(m) - 1;
            unsigned int base = 0u;
            if (lane == leader) base = atomicAdd(&s_cnt, (unsigned int)__popcll(m));
            base = __shfl(base, leader);
            if (selp) {
                unsigned int off = base + (unsigned int)__popcll(m & ((1ull << lane) - 1ull));
                if (off < SORTN) sel[off] = ((ull)(~key) << 32) | (ull)(unsigned int)n;
            }
        }
    }
    __syncthreads();
    const unsigned int C = s_cnt;
    for (int s = (int)C + t; s < SORTN; s += 1024) sel[s] = ~0ull;
    __syncthreads();

    for (unsigned int k = 2; k <= SORTN; k <<= 1) {
        for (unsigned int j = k >> 1; j > 0; j >>= 1) {
            #pragma unroll
            for (int r = 0; r < SORTN / 1024; ++r) {
                int i = (r << 10) + t;
                int l = i ^ (int)j;
                if (l > i) {
                    ull a  = sel[i];
                    ull bq = sel[l];
                    bool up = ((i & (int)k) == 0);
                    if ((a > bq) == up) { sel[i] = bq; sel[l] = a; }
                }
            }
            __syncthreads();
        }
    }

    ull ss[6];
    #pragma unroll
    for (int e = 0; e < 6; ++e) ss[e] = sel[(e << 10) + t];
    __syncthreads();

    float4 rbox[6];
    float  rarea[6];
    #pragma unroll
    for (int e = 0; e < 6; ++e) {
        int s = (e << 10) + t;
        float4 bx = make_float4(0.f, 0.f, 0.f, 0.f);
        bool ok = false;
        if (s < PRE_NMS) {
            unsigned int key = ~(unsigned int)(ss[e] >> 32);
            unsigned int n   = (unsigned int)(ss[e] & 0xFFFFFFFFull);
            float4 a = anc4[n];
            float4 d = bbox4[n];
            float dy = d.x * 0.1f, dx = d.y * 0.1f, dh = d.z * 0.2f, dw = d.w * 0.2f;
            float h  = a.z - a.x;
            float w  = a.w - a.y;
            float cy = a.x + 0.5f * h;
            float cx = a.y + 0.5f * w;
            cy = cy + dy * h;
            cx = cx + dx * w;
            h  = h * expf(dh);
            w  = w * expf(dw);
            float y1 = cy - 0.5f * h;
            float x1 = cx - 0.5f * w;
            float y2 = y1 + h;
            float x2 = x1 + w;
            y1 = fminf(fmaxf(y1, 0.f), 1.f);
            x1 = fminf(fmaxf(x1, 0.f), 1.f);
            y2 = fminf(fmaxf(y2, 0.f), 1.f);
            x2 = fminf(fmaxf(x2, 0.f), 1.f);
            bx = make_float4(y1, x1, y2, x2);
            ok = (key >= SCORE_THRES_BITS);
        }
        rbox[e]  = bx;
        rarea[e] = (bx.z - bx.x) * (bx.w - bx.y);
        boxes[s] = bx;
        ull am = __ballot(ok ? 1 : 0);
        if (lane == 0) s_alive[wv + (e << 4)] = am;
    }

    int emitted = 0;
    for (;;) {
        __syncthreads();
        if (emitted == PROP) break;
        ull w0 = s_alive[lane];
        ull w1 = (lane < 32) ? s_alive[64 + lane] : 0ull;
        ull nz0 = __ballot(w0 != 0ull ? 1 : 0);
        ull nz1 = __ballot(w1 != 0ull ? 1 : 0);
        int pick = -1;
        if (nz0) {
            int wd = __ffsll(nz0) - 1;
            ull wval = __shfl(w0, wd);
            pick = (wd << 6) + __ffsll(wval) - 1;
        } else if (nz1) {
            int wd = __ffsll(nz1) - 1;
            ull wval = __shfl(w1, wd);
            pick = ((wd + 64) << 6) + __ffsll(wval) - 1;
        }
        if (pick < 0) break;
        __syncthreads();

        if (t < 4) outb[(emitted << 2) + t] = reinterpret_cast<const float*>(s_big)[(pick << 2) + t];

        float4 p = boxes[pick];
        float parea = (p.z - p.x) * (p.w - p.y);
        #pragma unroll
        for (int e = 0; e < 6; ++e) {
            float4 bb  = rbox[e];
            float yy1 = fmaxf(p.x, bb.x);
            float xx1 = fmaxf(p.y, bb.y);
            float yy2 = fminf(p.z, bb.z);
            float xx2 = fminf(p.w, bb.w);
            float ih  = fmaxf(yy2 - yy1, 0.f);
            float iw  = fmaxf(xx2 - xx1, 0.f);
            float inter = ih * iw;
            float denom = ((parea + rarea[e]) - inter) + EPS_F;
            bool  sup   = ((double)inter > M_D * (double)denom);
            ull m = __ballot(sup ? 1 : 0);
            int word = wv + (e << 4);
            if (word == (pick >> 6)) m |= (1ull << (pick & 63));
            if (lane == 0) s_alive[word] &= ~m;
        }
        ++emitted;
    }

    for (int i = (emitted << 2) + t; i < PROP * 4; i += 1024) outb[i] = 0.f;
}

extern "C" void kernel_launch(void* const* d_in, const int* in_sizes, int n_in,
                              void* d_out, int out_size, void* d_ws, size_t ws_size,
                              hipStream_t stream) {
    const float* rpn_probs = (const float*)d_in[0];
    const float* rpn_bbox  = (const float*)d_in[1];
    const float* anchors   = (const float*)d_in[2];
    float* out = (float*)d_out;

    // ws layout: boxes (8*6144 float4) | alive (8*96 u64) | pad | matrix @1MiB
    const size_t BOX_OFF   = 0;
    const size_t ALIVE_OFF = (size_t)BATCH * NSLOT * sizeof(float4);          // 786432
    const size_t MAT_OFF   = 1u << 20;                                        // 1 MiB
    const size_t WS_NEED   = MAT_OFF + (size_t)BATCH * PRE_NMS * MROW * 8;    // ~37.9 MB

    if (d_ws != nullptr && ws_size >= WS_NEED) {
        char* ws = (char*)d_ws;
        float4* boxes_ws = (float4*)(ws + BOX_OFF);
        ull*    alive_ws = (ull*)(ws + ALIVE_OFF);
        ull*    mat      = (ull*)(ws + MAT_OFF);

        hipLaunchKernelGGL(select_kernel, dim3(BATCH), dim3(1024), 0, stream,
                           rpn_probs, rpn_bbox, anchors, boxes_ws, alive_ws);
        hipLaunchKernelGGL(iou_matrix_kernel, dim3(PRE_NMS / 16, BATCH), dim3(1024), 0, stream,
                           boxes_ws, mat);
        hipLaunchKernelGGL(nms_scan_kernel, dim3(BATCH), dim3(64), 0, stream,
                           boxes_ws, alive_ws, mat, out);
    } else {
        hipLaunchKernelGGL(proposal_fallback, dim3(BATCH), dim3(1024), 0, stream,
                           rpn_probs, rpn_bbox, anchors, out);
    }
}

// Round 3
// 1116.035 us; speedup vs baseline: 2.0868x; 1.4516x over previous
//
#include <hip/hip_runtime.h>
#include <cstdint>
#include <cstddef>

#pragma clang fp contract(off)

#define BATCH    8
#define NANCH    261888
#define PRE_NMS  6000
#define PROP     1000
#define SORTN    8192
#define NSLOT    6144          /* 6 * 1024 */
#define MROW     96            /* u64 words per suppression row (94 used + 2 pad) */
#define NBIN     16384
#define CHUNK    4092          /* NANCH / 64 */
#define SCORE_THRES_BITS 0x3F000000u   /* bits of 0.5f */
#define EPS_F    1e-8f
/* midpoint between pred(0.7f) and 0.7f = 23488101 * 2^-25, exact in double.
   RN(inter/denom) >= 0.7f  <=>  inter > M_D * denom  (exact: 25b x 24b product). */
#define M_D      0.6999999582767486572265625

typedef unsigned long long ull;
typedef unsigned int u32;

// ---------------------------------------------------------------------------
// Kernel A: per-batch 16384-bin histogram of score key >> 16.
// grid (64, BATCH) x 256. LDS-private hist, paired-u64 atomic flush.
// ---------------------------------------------------------------------------
__global__ __launch_bounds__(256)
void hist_kernel(const float* __restrict__ rpn_probs, u32* __restrict__ ghist)
{
    __shared__ u32 h[NBIN];   // 64 KB
    const int t   = threadIdx.x;
    const int blk = blockIdx.x;
    const int b   = blockIdx.y;

    for (int j = t; j < NBIN; j += 256) h[j] = 0u;
    __syncthreads();

    const size_t base = (size_t)b * NANCH * 2;
    const int n0 = blk * CHUNK;
    for (int i = t; i < CHUNK; i += 256) {
        int n = n0 + i;                       // n < NANCH guaranteed (64*4092 = NANCH)
        u32 key = __float_as_uint(rpn_probs[base + 2 * (size_t)n + 1]);
        atomicAdd(&h[key >> 16], 1u);
    }
    __syncthreads();

    ull* gh2 = reinterpret_cast<ull*>(ghist + (size_t)b * NBIN);
    for (int j = t; j < NBIN / 2; j += 256) {
        u32 lo = h[2 * j], hi = h[2 * j + 1];
        if (lo | hi) atomicAdd(&gh2[j], ((ull)hi << 32) | (ull)lo);  // no cross-carry: sums < 2^32
    }
}

// ---------------------------------------------------------------------------
// Kernel B: find coarse threshold bin (suffix scan from the top).
// grid (BATCH) x 1024, 16 bins/thread.
// ---------------------------------------------------------------------------
__global__ __launch_bounds__(1024)
void findT_kernel(const u32* __restrict__ ghist, u32* __restrict__ Tc)
{
    __shared__ u32 cum[1024];
    const int t = threadIdx.x;
    const int b = blockIdx.x;
    const u32* h = ghist + (size_t)b * NBIN + t * 16;

    u32 loc[16];
    u32 s = 0;
    #pragma unroll
    for (int i = 0; i < 16; ++i) { loc[i] = h[i]; s += loc[i]; }
    cum[t] = s;
    for (int d = 1; d < 1024; d <<= 1) {
        __syncthreads();
        u32 v = (t + d < 1024) ? cum[t + d] : 0u;
        __syncthreads();
        cum[t] += v;
    }
    __syncthreads();
    u32 above = (t < 1023) ? cum[t + 1] : 0u;   // count of keys in bins > my chunk
    if (above < PRE_NMS && above + s >= PRE_NMS) {
        u32 run = above;
        int bin = t * 16;
        for (int i = 15; i >= 0; --i) {
            run += loc[i];
            if (run >= PRE_NMS) { bin = t * 16 + i; break; }
        }
        Tc[b] = (u32)bin << 16;
    }
}

// ---------------------------------------------------------------------------
// Kernel C: compact keys >= Tc[b] into selbuf (unordered; sort fixes order).
// grid (64, BATCH) x 256.
// ---------------------------------------------------------------------------
__global__ __launch_bounds__(256)
void compact_kernel(const float* __restrict__ rpn_probs,
                    const u32* __restrict__ Tc,
                    ull* __restrict__ selbuf, u32* __restrict__ cnt8)
{
    const int t    = threadIdx.x;
    const int blk  = blockIdx.x;
    const int b    = blockIdx.y;
    const int lane = t & 63;
    const u32 T = Tc[b];

    const size_t base = (size_t)b * NANCH * 2;
    ull* sb = selbuf + (size_t)b * SORTN;
    const int n0 = blk * CHUNK;

    for (int i = t; i < CHUNK; i += 256) {
        int n = n0 + i;
        u32 key = __float_as_uint(rpn_probs[base + 2 * (size_t)n + 1]);
        bool selp = (key >= T);
        ull m = __ballot(selp ? 1 : 0);
        if (m) {
            int leader = __ffsll(m) - 1;
            u32 bs = 0;
            if (lane == leader) bs = atomicAdd(&cnt8[b], (u32)__popcll(m));
            bs = __shfl(bs, leader);
            if (selp) {
                u32 off = bs + (u32)__popcll(m & ((1ull << lane) - 1ull));
                if (off < SORTN) sb[off] = ((ull)(~key) << 32) | (ull)(u32)n;
            }
        }
    }
}

// ---------------------------------------------------------------------------
// Kernel D: per-batch bitonic sort of 8192 keys + box decode + alive words.
// grid (BATCH) x 1024.
// ---------------------------------------------------------------------------
__global__ __launch_bounds__(1024)
void sort_decode_kernel(const float* __restrict__ rpn_bbox,
                        const float* __restrict__ anchors,
                        const ull* __restrict__ selbuf,
                        const u32* __restrict__ cnt8,
                        float4* __restrict__ boxes_ws,
                        ull* __restrict__ alive_ws)
{
    __shared__ ull sel[SORTN];   // 64 KB
    const int b    = blockIdx.x;
    const int t    = threadIdx.x;
    const int lane = t & 63;
    const int wv   = t >> 6;

    const u32 C = min(cnt8[b], (u32)SORTN);
    const ull* sb = selbuf + (size_t)b * SORTN;
    #pragma unroll
    for (int r = 0; r < SORTN / 1024; ++r) {
        int i = (r << 10) + t;
        sel[i] = (i < (int)C) ? sb[i] : ~0ull;
    }
    __syncthreads();

    for (unsigned int k = 2; k <= SORTN; k <<= 1) {
        for (unsigned int j = k >> 1; j > 0; j >>= 1) {
            #pragma unroll
            for (int r = 0; r < SORTN / 1024; ++r) {
                int i = (r << 10) + t;
                int l = i ^ (int)j;
                if (l > i) {
                    ull a  = sel[i];
                    ull bq = sel[l];
                    bool up = ((i & (int)k) == 0);
                    if ((a > bq) == up) { sel[i] = bq; sel[l] = a; }
                }
            }
            __syncthreads();
        }
    }

    const float4* bbox4 = reinterpret_cast<const float4*>(rpn_bbox + (size_t)b * NANCH * 4);
    const float4* anc4  = reinterpret_cast<const float4*>(anchors  + (size_t)b * NANCH * 4);

    #pragma unroll
    for (int e = 0; e < 6; ++e) {
        int s = (e << 10) + t;
        float4 bx = make_float4(0.f, 0.f, 0.f, 0.f);
        bool ok = false;
        if (s < PRE_NMS) {
            ull ss = sel[s];
            u32 key = ~(u32)(ss >> 32);
            u32 n   = (u32)(ss & 0xFFFFFFFFull);
            float4 a = anc4[n];
            float4 d = bbox4[n];
            float dy = d.x * 0.1f, dx = d.y * 0.1f, dh = d.z * 0.2f, dw = d.w * 0.2f;
            float h  = a.z - a.x;
            float w  = a.w - a.y;
            float cy = a.x + 0.5f * h;
            float cx = a.y + 0.5f * w;
            cy = cy + dy * h;
            cx = cx + dx * w;
            h  = h * expf(dh);
            w  = w * expf(dw);
            float y1 = cy - 0.5f * h;
            float x1 = cx - 0.5f * w;
            float y2 = y1 + h;
            float x2 = x1 + w;
            y1 = fminf(fmaxf(y1, 0.f), 1.f);
            x1 = fminf(fmaxf(x1, 0.f), 1.f);
            y2 = fminf(fmaxf(y2, 0.f), 1.f);
            x2 = fminf(fmaxf(x2, 0.f), 1.f);
            bx = make_float4(y1, x1, y2, x2);
            ok = (key >= SCORE_THRES_BITS);
        }
        boxes_ws[(size_t)b * NSLOT + s] = bx;
        ull am = __ballot(ok ? 1 : 0);
        if (lane == 0) alive_ws[(size_t)b * MROW + wv + (e << 4)] = am;
    }
}

// ---------------------------------------------------------------------------
// Kernel E: suppression bit-matrix. Row r, bit j set iff j>r and IoU>=0.7.
// grid (375, BATCH) x 1024 (16 waves -> 16 rows/block).
// ---------------------------------------------------------------------------
__global__ __launch_bounds__(1024)
void iou_matrix_kernel(const float4* __restrict__ boxes_ws,
                       ull* __restrict__ mat)
{
    __shared__ float4 sbox[NSLOT];   // 96 KB
    const int b    = blockIdx.y;
    const int t    = threadIdx.x;
    const int lane = t & 63;
    const int wv   = t >> 6;

    const float4* bws = boxes_ws + (size_t)b * NSLOT;
    #pragma unroll
    for (int i = 0; i < 6; ++i) sbox[(i << 10) + t] = bws[(i << 10) + t];
    __syncthreads();

    const int r = (blockIdx.x << 4) + wv;
    if (r >= PRE_NMS) return;

    float4 p = sbox[r];
    float pa = (p.z - p.x) * (p.w - p.y);
    ull* row = mat + ((size_t)b * PRE_NMS + r) * MROW;

    const int k0 = r >> 6;
    for (int w = lane; w < k0; w += 64) row[w] = 0;
    if (lane < 2) row[94 + lane] = 0;

    for (int k = k0; k < 94; ++k) {
        int c = (k << 6) + lane;
        float4 q = sbox[c];
        float qa  = (q.z - q.x) * (q.w - q.y);
        float yy1 = fmaxf(p.x, q.x);
        float xx1 = fmaxf(p.y, q.y);
        float yy2 = fminf(p.z, q.z);
        float xx2 = fminf(p.w, q.w);
        float inter = fmaxf(yy2 - yy1, 0.f) * fmaxf(xx2 - xx1, 0.f);
        float denom = ((pa + qa) - inter) + EPS_F;
        bool sup = ((double)inter > M_D * (double)denom) && (c > r);
        ull m = __ballot(sup ? 1 : 0);
        if (lane == 0) row[k] = m;
    }
}

// ---------------------------------------------------------------------------
// Kernel F: word-walk greedy scan, one wave per batch.
// Every candidate not suppressed by an earlier pick IS a pick, so walk the
// 94 words in order: resolve intra-word with the (prefetched) diagonal block,
// then OR picked rows into the alive registers (16-deep load batches).
// ---------------------------------------------------------------------------
__global__ __launch_bounds__(64)
void nms_scan_kernel(const float4* __restrict__ boxes_ws,
                     const ull* __restrict__ alive_ws,
                     const ull* __restrict__ mat,
                     float* __restrict__ out)
{
    const int b    = blockIdx.x;
    const int lane = threadIdx.x;

    __shared__ int picks[PROP];

    // lane l (<48) holds alive words 2l, 2l+1 (words 94,95 are zero by construction)
    ull aw0 = 0, aw1 = 0;
    if (lane < 48) {
        const ull* aw = alive_ws + (size_t)b * MROW + 2 * lane;
        aw0 = aw[0]; aw1 = aw[1];
    }

    const ull* mb = mat + (size_t)b * PRE_NMS * MROW;
    // prefetch diagonal block for word 0: lane i -> mat[i][word 0]
    ull diag = mb[(size_t)lane * MROW];
    int cnt = 0;

    for (int k = 0; k < 94; ++k) {
        ull wval = __shfl((k & 1) ? aw1 : aw0, k >> 1);   // alive word k (uniform)
        ull diag_cur = diag;
        if (k < 93) {                                     // prefetch word k+1 diagonal
            int r = ((k + 1) << 6) + lane;
            diag = (r < PRE_NMS) ? mb[(size_t)r * MROW + (k + 1)] : 0ull;
        }
        if (wval == 0ull) continue;

        // ---- resolve picks within word k (serial, readlane-based: no LDS shuffles)
        ull m = wval;
        ull pickedm = 0ull;
        while (m) {
            int p  = __ffsll(m) - 1;
            int ps = __builtin_amdgcn_readfirstlane(p);
            u32 lo = (u32)__builtin_amdgcn_readlane((int)(u32)diag_cur, ps);
            u32 hi = (u32)__builtin_amdgcn_readlane((int)(u32)(diag_cur >> 32), ps);
            ull sup = ((ull)hi << 32) | (ull)lo;          // bits suppressed by pick ps (j > ps)
            if (lane == 0) picks[cnt] = (k << 6) + ps;
            ++cnt;
            pickedm |= (1ull << ps);
            m &= ~(sup | (1ull << ps));
            if (cnt == PROP) break;
        }

        // ---- OR picked rows into alive regs, 16 rows per batch of loads
        ull t = pickedm;
        while (t) {
            ull lx[16], ly[16];
            ull tt = t;
            #pragma unroll
            for (int g = 0; g < 16; ++g) {
                lx[g] = 0; ly[g] = 0;
                if (tt) {
                    int p = __ffsll(tt) - 1;
                    tt &= tt - 1ull;
                    if (lane < 48) {
                        const ull* rp = mb + (size_t)((k << 6) + p) * MROW + 2 * lane;
                        ulonglong2 v = *reinterpret_cast<const ulonglong2*>(rp);
                        lx[g] = v.x; ly[g] = v.y;
                    }
                }
            }
            t = tt;
            ull rx = 0, ry = 0;
            #pragma unroll
            for (int g = 0; g < 16; ++g) { rx |= lx[g]; ry |= ly[g]; }
            aw0 &= ~rx; aw1 &= ~ry;
        }
        // word k fully consumed (every bit picked or suppressed)
        if (lane == (k >> 1)) { if (k & 1) aw1 = 0ull; else aw0 = 0ull; }
        if (cnt == PROP) break;
    }

    __syncthreads();
    const float4* bws = boxes_ws + (size_t)b * NSLOT;
    float4* ob = reinterpret_cast<float4*>(out + (size_t)b * PROP * 4);
    for (int i = lane; i < PROP; i += 64) {
        float4 v = make_float4(0.f, 0.f, 0.f, 0.f);
        if (i < cnt) v = bws[picks[i]];
        ob[i] = v;
    }
}

// ---------------------------------------------------------------------------
// Fallback: round-1 monolithic kernel (used if ws too small). Verified exact.
// ---------------------------------------------------------------------------
__device__ __forceinline__ void hist_add_f(unsigned int* hist, unsigned int bin, bool valid) {
    const int lane = threadIdx.x & 63;
    ull todo = __ballot(valid ? 1 : 0);
    #pragma unroll
    for (int it = 0; it < 3; ++it) {
        if (!todo) return;
        int leader = __ffsll(todo) - 1;
        unsigned int lbin = __shfl(bin, leader);
        ull grp = __ballot((valid && (bin == lbin)) ? 1 : 0);
        if (lane == leader) atomicAdd(&hist[lbin], (unsigned int)__popcll(grp));
        todo &= ~grp;
    }
    if ((todo >> lane) & 1ull) atomicAdd(&hist[bin], 1u);
}

__global__ __launch_bounds__(1024)
void proposal_fallback(const float* __restrict__ rpn_probs,
                       const float* __restrict__ rpn_bbox,
                       const float* __restrict__ anchors,
                       float* __restrict__ out)
{
    const int b    = blockIdx.x;
    const int t    = threadIdx.x;
    const int lane = t & 63;
    const int wv   = t >> 6;

    const float2* __restrict__ probs2 = reinterpret_cast<const float2*>(rpn_probs + (size_t)b * NANCH * 2);
    const float4* __restrict__ bbox4  = reinterpret_cast<const float4*>(rpn_bbox  + (size_t)b * NANCH * 4);
    const float4* __restrict__ anc4   = reinterpret_cast<const float4*>(anchors   + (size_t)b * NANCH * 4);
    float* __restrict__ outb = out + (size_t)b * PROP * 4;

    __shared__ __align__(16) char s_big[NSLOT * 16];
    __shared__ ull          s_alive[96];
    __shared__ unsigned int s_hist[256];
    __shared__ unsigned int s_pref;
    __shared__ unsigned int s_targ;
    __shared__ unsigned int s_cnt;

    ull*    sel   = reinterpret_cast<ull*>(s_big);
    float4* boxes = reinterpret_cast<float4*>(s_big);

    const int ITER = (NANCH + 1023) >> 10;

    if (t == 0) { s_pref = 0u; s_targ = PRE_NMS; s_cnt = 0u; }

    for (int p = 0; p < 4; ++p) {
        if (t < 256) s_hist[t] = 0u;
        __syncthreads();
        const unsigned int pref  = s_pref;
        const int          shift = 8 * (3 - p);
        const unsigned int pmask = (p == 0) ? 0u : (0xFFFFFFFFu << (shift + 8));
        for (int i = 0; i < ITER; ++i) {
            int  n     = (i << 10) + t;
            bool valid = (n < NANCH);
            unsigned int key = 0u;
            if (valid) key = __float_as_uint(probs2[n].y);
            bool match = valid && ((key & pmask) == (pref & pmask));
            hist_add_f(s_hist, (key >> shift) & 0xFFu, match);
        }
        __syncthreads();
        if (t == 0) {
            unsigned int target = s_targ;
            unsigned int acc = 0u;
            int v = 255;
            for (; v >= 0; --v) {
                unsigned int h = s_hist[v];
                if (acc + h >= target) break;
                acc += h;
            }
            if (v < 0) v = 0;
            s_pref = pref | ((unsigned int)v << shift);
            s_targ = target - acc;
        }
        __syncthreads();
    }

    const unsigned int T = s_pref;
    __syncthreads();

    for (int i = 0; i < ITER; ++i) {
        int  n     = (i << 10) + t;
        bool valid = (n < NANCH);
        unsigned int key = 0u;
        if (valid) key = __float_as_uint(probs2[n].y);
        bool selp = valid && (key >= T);
        ull  m    = __ballot(selp ? 1 : 0);
        if (m) {
            int leader = __ffsll(m) - 1;
            unsigned int base = 0u;
            if (lane == leader) base = atomicAdd(&s_cnt, (unsigned int)__popcll(m));
            base = __shfl(base, leader);
            if (selp) {
                unsigned int off = base + (unsigned int)__popcll(m & ((1ull << lane) - 1ull));
                if (off < SORTN) sel[off] = ((ull)(~key) << 32) | (ull)(unsigned int)n;
            }
        }
    }
    __syncthreads();
    const unsigned int C = s_cnt;
    for (int s = (int)C + t; s < SORTN; s += 1024) sel[s] = ~0ull;
    __syncthreads();

    for (unsigned int k = 2; k <= SORTN; k <<= 1) {
        for (unsigned int j = k >> 1; j > 0; j >>= 1) {
            #pragma unroll
            for (int r = 0; r < SORTN / 1024; ++r) {
                int i = (r << 10) + t;
                int l = i ^ (int)j;
                if (l > i) {
                    ull a  = sel[i];
                    ull bq = sel[l];
                    bool up = ((i & (int)k) == 0);
                    if ((a > bq) == up) { sel[i] = bq; sel[l] = a; }
                }
            }
            __syncthreads();
        }
    }

    ull ss[6];
    #pragma unroll
    for (int e = 0; e < 6; ++e) ss[e] = sel[(e << 10) + t];
    __syncthreads();

    float4 rbox[6];
    float  rarea[6];
    #pragma unroll
    for (int e = 0; e < 6; ++e) {
        int s = (e << 10) + t;
        float4 bx = make_float4(0.f, 0.f, 0.f, 0.f);
        bool ok = false;
        if (s < PRE_NMS) {
            unsigned int key = ~(unsigned int)(ss[e] >> 32);
            unsigned int n   = (unsigned int)(ss[e] & 0xFFFFFFFFull);
            float4 a = anc4[n];
            float4 d = bbox4[n];
            float dy = d.x * 0.1f, dx = d.y * 0.1f, dh = d.z * 0.2f, dw = d.w * 0.2f;
            float h  = a.z - a.x;
            float w  = a.w - a.y;
            float cy = a.x + 0.5f * h;
            float cx = a.y + 0.5f * w;
            cy = cy + dy * h;
            cx = cx + dx * w;
            h  = h * expf(dh);
            w  = w * expf(dw);
            float y1 = cy - 0.5f * h;
            float x1 = cx - 0.5f * w;
            float y2 = y1 + h;
            float x2 = x1 + w;
            y1 = fminf(fmaxf(y1, 0.f), 1.f);
            x1 = fminf(fmaxf(x1, 0.f), 1.f);
            y2 = fminf(fmaxf(y2, 0.f), 1.f);
            x2 = fminf(fmaxf(x2, 0.f), 1.f);
            bx = make_float4(y1, x1, y2, x2);
            ok = (key >= SCORE_THRES_BITS);
        }
        rbox[e]  = bx;
        rarea[e] = (bx.z - bx.x) * (bx.w - bx.y);
        boxes[s] = bx;
        ull am = __ballot(ok ? 1 : 0);
        if (lane == 0) s_alive[wv + (e << 4)] = am;
    }

    int emitted = 0;
    for (;;) {
        __syncthreads();
        if (emitted == PROP) break;
        ull w0 = s_alive[lane];
        ull w1 = (lane < 32) ? s_alive[64 + lane] : 0ull;
        ull nz0 = __ballot(w0 != 0ull ? 1 : 0);
        ull nz1 = __ballot(w1 != 0ull ? 1 : 0);
        int pick = -1;
        if (nz0) {
            int wd = __ffsll(nz0) - 1;
            ull wvv = __shfl(w0, wd);
            pick = (wd << 6) + __ffsll(wvv) - 1;
        } else if (nz1) {
            int wd = __ffsll(nz1) - 1;
            ull wvv = __shfl(w1, wd);
            pick = ((wd + 64) << 6) + __ffsll(wvv) - 1;
        }
        if (pick < 0) break;
        __syncthreads();

        if (t < 4) outb[(emitted << 2) + t] = reinterpret_cast<const float*>(s_big)[(pick << 2) + t];

        float4 p = boxes[pick];
        float parea = (p.z - p.x) * (p.w - p.y);
        #pragma unroll
        for (int e = 0; e < 6; ++e) {
            float4 bb  = rbox[e];
            float yy1 = fmaxf(p.x, bb.x);
            float xx1 = fmaxf(p.y, bb.y);
            float yy2 = fminf(p.z, bb.z);
            float xx2 = fminf(p.w, bb.w);
            float ih  = fmaxf(yy2 - yy1, 0.f);
            float iw  = fmaxf(xx2 - xx1, 0.f);
            float inter = ih * iw;
            float denom = ((parea + rarea[e]) - inter) + EPS_F;
            bool  sup   = ((double)inter > M_D * (double)denom);
            ull m = __ballot(sup ? 1 : 0);
            int word = wv + (e << 4);
            if (word == (pick >> 6)) m |= (1ull << (pick & 63));
            if (lane == 0) s_alive[word] &= ~m;
        }
        ++emitted;
    }

    for (int i = (emitted << 2) + t; i < PROP * 4; i += 1024) outb[i] = 0.f;
}

extern "C" void kernel_launch(void* const* d_in, const int* in_sizes, int n_in,
                              void* d_out, int out_size, void* d_ws, size_t ws_size,
                              hipStream_t stream) {
    const float* rpn_probs = (const float*)d_in[0];
    const float* rpn_bbox  = (const float*)d_in[1];
    const float* anchors   = (const float*)d_in[2];
    float* out = (float*)d_out;

    // ws layout (low MiB): boxes | alive | misc(Tc, cnt8). [1MiB..): mat.
    // ghist + selbuf live INSIDE the mat region (consumed before mat is written).
    const size_t BOX_OFF   = 0;
    const size_t ALIVE_OFF = (size_t)BATCH * NSLOT * sizeof(float4);           // 786432
    const size_t MISC_OFF  = 832 * 1024;                                       // Tc[8], cnt8[8]
    const size_t MAT_OFF   = 1u << 20;
    const size_t GHIST_OFF = MAT_OFF;                                          // 8*16384*4 = 512 KB
    const size_t SELB_OFF  = MAT_OFF + (size_t)BATCH * NBIN * 4;               // 8*8192*8 = 512 KB
    const size_t WS_NEED   = MAT_OFF + (size_t)BATCH * PRE_NMS * MROW * 8;     // ~37.9 MB

    if (d_ws != nullptr && ws_size >= WS_NEED) {
        char* ws = (char*)d_ws;
        float4* boxes_ws = (float4*)(ws + BOX_OFF);
        ull*    alive_ws = (ull*)(ws + ALIVE_OFF);
        u32*    Tc       = (u32*)(ws + MISC_OFF);
        u32*    cnt8     = (u32*)(ws + MISC_OFF + 64);
        u32*    ghist    = (u32*)(ws + GHIST_OFF);
        ull*    selbuf   = (ull*)(ws + SELB_OFF);
        ull*    mat      = (ull*)(ws + MAT_OFF);

        hipMemsetAsync(ghist, 0, (size_t)BATCH * NBIN * 4, stream);
        hipMemsetAsync(cnt8, 0, 64, stream);
        hipLaunchKernelGGL(hist_kernel, dim3(64, BATCH), dim3(256), 0, stream,
                           rpn_probs, ghist);
        hipLaunchKernelGGL(findT_kernel, dim3(BATCH), dim3(1024), 0, stream,
                           ghist, Tc);
        hipLaunchKernelGGL(compact_kernel, dim3(64, BATCH), dim3(256), 0, stream,
                           rpn_probs, Tc, selbuf, cnt8);
        hipLaunchKernelGGL(sort_decode_kernel, dim3(BATCH), dim3(1024), 0, stream,
                           rpn_bbox, anchors, selbuf, cnt8, boxes_ws, alive_ws);
        hipLaunchKernelGGL(iou_matrix_kernel, dim3(PRE_NMS / 16, BATCH), dim3(1024), 0, stream,
                           boxes_ws, mat);
        hipLaunchKernelGGL(nms_scan_kernel, dim3(BATCH), dim3(64), 0, stream,
                           boxes_ws, alive_ws, mat, out);
    } else {
        hipLaunchKernelGGL(proposal_fallback, dim3(BATCH), dim3(1024), 0, stream,
                           rpn_probs, rpn_bbox, anchors, out);
    }
}

// Round 4
// 812.960 us; speedup vs baseline: 2.8648x; 1.3728x over previous
//
#include <hip/hip_runtime.h>
#include <cstdint>
#include <cstddef>

#pragma clang fp contract(off)

#define BATCH    8
#define NANCH    261888
#define PRE_NMS  6000
#define PROP     1000
#define SORTN    8192
#define NSLOT    6144          /* 6 * 1024 */
#define MROW     96            /* u64 words per suppression row (94 used + 2 pad) */
#define NBIN     16384
#define CHUNK    4092          /* NANCH / 64 */
#define SCORE_THRES_BITS 0x3F000000u   /* bits of 0.5f */
#define EPS_F    1e-8f
/* midpoint between pred(0.7f) and 0.7f = 23488101 * 2^-25, exact in double.
   RN(inter/denom) >= 0.7f  <=>  inter > M_D * denom  (exact: 25b x 24b product). */
#define M_D      0.6999999582767486572265625

typedef unsigned long long ull;
typedef unsigned int u32;

// ---------------------------------------------------------------------------
// Kernel A: per-batch 16384-bin histogram of score key >> 16.
// grid (64, BATCH) x 256. LDS-private hist, paired-u64 atomic flush.
// ---------------------------------------------------------------------------
__global__ __launch_bounds__(256)
void hist_kernel(const float* __restrict__ rpn_probs, u32* __restrict__ ghist)
{
    __shared__ u32 h[NBIN];   // 64 KB
    const int t   = threadIdx.x;
    const int blk = blockIdx.x;
    const int b   = blockIdx.y;

    for (int j = t; j < NBIN; j += 256) h[j] = 0u;
    __syncthreads();

    const size_t base = (size_t)b * NANCH * 2;
    const int n0 = blk * CHUNK;
    for (int i = t; i < CHUNK; i += 256) {
        int n = n0 + i;                       // n < NANCH guaranteed (64*4092 = NANCH)
        u32 key = __float_as_uint(rpn_probs[base + 2 * (size_t)n + 1]);
        atomicAdd(&h[key >> 16], 1u);
    }
    __syncthreads();

    ull* gh2 = reinterpret_cast<ull*>(ghist + (size_t)b * NBIN);
    for (int j = t; j < NBIN / 2; j += 256) {
        u32 lo = h[2 * j], hi = h[2 * j + 1];
        if (lo | hi) atomicAdd(&gh2[j], ((ull)hi << 32) | (ull)lo);  // no cross-carry: sums < 2^32
    }
}

// ---------------------------------------------------------------------------
// Kernel B: find coarse threshold bin (suffix scan from the top).
// grid (BATCH) x 1024, 16 bins/thread.
// ---------------------------------------------------------------------------
__global__ __launch_bounds__(1024)
void findT_kernel(const u32* __restrict__ ghist, u32* __restrict__ Tc)
{
    __shared__ u32 cum[1024];
    const int t = threadIdx.x;
    const int b = blockIdx.x;
    const u32* h = ghist + (size_t)b * NBIN + t * 16;

    u32 loc[16];
    u32 s = 0;
    #pragma unroll
    for (int i = 0; i < 16; ++i) { loc[i] = h[i]; s += loc[i]; }
    cum[t] = s;
    for (int d = 1; d < 1024; d <<= 1) {
        __syncthreads();
        u32 v = (t + d < 1024) ? cum[t + d] : 0u;
        __syncthreads();
        cum[t] += v;
    }
    __syncthreads();
    u32 above = (t < 1023) ? cum[t + 1] : 0u;   // count of keys in bins > my chunk
    if (above < PRE_NMS && above + s >= PRE_NMS) {
        u32 run = above;
        int bin = t * 16;
        for (int i = 15; i >= 0; --i) {
            run += loc[i];
            if (run >= PRE_NMS) { bin = t * 16 + i; break; }
        }
        Tc[b] = (u32)bin << 16;
    }
}

// ---------------------------------------------------------------------------
// Kernel C: compact keys >= Tc[b] into selbuf (unordered; ranking fixes order).
// grid (64, BATCH) x 256.
// ---------------------------------------------------------------------------
__global__ __launch_bounds__(256)
void compact_kernel(const float* __restrict__ rpn_probs,
                    const u32* __restrict__ Tc,
                    ull* __restrict__ selbuf, u32* __restrict__ cnt8)
{
    const int t    = threadIdx.x;
    const int blk  = blockIdx.x;
    const int b    = blockIdx.y;
    const int lane = t & 63;
    const u32 T = Tc[b];

    const size_t base = (size_t)b * NANCH * 2;
    ull* sb = selbuf + (size_t)b * SORTN;
    const int n0 = blk * CHUNK;

    for (int i = t; i < CHUNK; i += 256) {
        int n = n0 + i;
        u32 key = __float_as_uint(rpn_probs[base + 2 * (size_t)n + 1]);
        bool selp = (key >= T);
        ull m = __ballot(selp ? 1 : 0);
        if (m) {
            int leader = __ffsll(m) - 1;
            u32 bs = 0;
            if (lane == leader) bs = atomicAdd(&cnt8[b], (u32)__popcll(m));
            bs = __shfl(bs, leader);
            if (selp) {
                u32 off = bs + (u32)__popcll(m & ((1ull << lane) - 1ull));
                if (off < SORTN) sb[off] = ((ull)(~key) << 32) | (ull)(u32)n;
            }
        }
    }
}

// ---------------------------------------------------------------------------
// Kernel D (NEW): rank-scatter. slot(i) = #{j : comp_j < comp_i} — identical
// to ascending sort of the unique composite keys. Decode + scatter + alive
// atomicOr fused. grid (32, BATCH) x 256; LDS-tiled comparison corpus.
// ---------------------------------------------------------------------------
__global__ __launch_bounds__(256)
void rank_decode_kernel(const float* __restrict__ rpn_bbox,
                        const float* __restrict__ anchors,
                        const ull* __restrict__ selbuf,
                        const u32* __restrict__ cnt8,
                        float4* __restrict__ boxes_ws,
                        ull* __restrict__ alive_ws)
{
    __shared__ ull tile[2048];   // 16 KB
    const int t = threadIdx.x;
    const int b = blockIdx.y;
    const u32 C = min(cnt8[b], (u32)SORTN);
    const ull* sb = selbuf + (size_t)b * SORTN;

    const int i = (blockIdx.x << 8) + t;
    const ull mykey = (i < (int)C) ? sb[i] : ~0ull;

    int rank = 0;
    for (u32 tb = 0; tb < C; tb += 2048) {
        const int m = (int)min((u32)2048, C - tb);
        __syncthreads();
        for (int j = t; j < m; j += 256) tile[j] = sb[tb + j];
        __syncthreads();
        int j = 0;
        for (; j + 8 <= m; j += 8) {
            #pragma unroll
            for (int u = 0; u < 8; ++u) rank += (tile[j + u] < mykey) ? 1 : 0;
        }
        for (; j < m; ++j) rank += (tile[j] < mykey) ? 1 : 0;
    }

    if (i < (int)C && rank < PRE_NMS) {
        const u32 key = ~(u32)(mykey >> 32);
        const u32 n   = (u32)(mykey & 0xFFFFFFFFull);
        const float4* bbox4 = reinterpret_cast<const float4*>(rpn_bbox + (size_t)b * NANCH * 4);
        const float4* anc4  = reinterpret_cast<const float4*>(anchors  + (size_t)b * NANCH * 4);
        float4 a = anc4[n];
        float4 d = bbox4[n];
        float dy = d.x * 0.1f, dx = d.y * 0.1f, dh = d.z * 0.2f, dw = d.w * 0.2f;
        float h  = a.z - a.x;
        float w  = a.w - a.y;
        float cy = a.x + 0.5f * h;
        float cx = a.y + 0.5f * w;
        cy = cy + dy * h;
        cx = cx + dx * w;
        h  = h * expf(dh);
        w  = w * expf(dw);
        float y1 = cy - 0.5f * h;
        float x1 = cx - 0.5f * w;
        float y2 = y1 + h;
        float x2 = x1 + w;
        y1 = fminf(fmaxf(y1, 0.f), 1.f);
        x1 = fminf(fmaxf(x1, 0.f), 1.f);
        y2 = fminf(fmaxf(y2, 0.f), 1.f);
        x2 = fminf(fmaxf(x2, 0.f), 1.f);
        boxes_ws[(size_t)b * NSLOT + rank] = make_float4(y1, x1, y2, x2);
        if (key >= SCORE_THRES_BITS) {
            atomicOr(&alive_ws[(size_t)b * MROW + (rank >> 6)], 1ull << (rank & 63));
        }
    }
}

// ---------------------------------------------------------------------------
// Kernel E: suppression bit-matrix. Row r, bit j set iff j>r and IoU>=0.7.
// grid (375, BATCH) x 1024 (16 waves -> 16 rows/block).
// ---------------------------------------------------------------------------
__global__ __launch_bounds__(1024)
void iou_matrix_kernel(const float4* __restrict__ boxes_ws,
                       ull* __restrict__ mat)
{
    __shared__ float4 sbox[NSLOT];   // 96 KB
    const int b    = blockIdx.y;
    const int t    = threadIdx.x;
    const int lane = t & 63;
    const int wv   = t >> 6;

    const float4* bws = boxes_ws + (size_t)b * NSLOT;
    #pragma unroll
    for (int i = 0; i < 6; ++i) sbox[(i << 10) + t] = bws[(i << 10) + t];
    __syncthreads();

    const int r = (blockIdx.x << 4) + wv;
    if (r >= PRE_NMS) return;

    float4 p = sbox[r];
    float pa = (p.z - p.x) * (p.w - p.y);
    ull* row = mat + ((size_t)b * PRE_NMS + r) * MROW;

    const int k0 = r >> 6;
    for (int w = lane; w < k0; w += 64) row[w] = 0;
    if (lane < 2) row[94 + lane] = 0;

    for (int k = k0; k < 94; ++k) {
        int c = (k << 6) + lane;
        float4 q = sbox[c];
        float qa  = (q.z - q.x) * (q.w - q.y);
        float yy1 = fmaxf(p.x, q.x);
        float xx1 = fmaxf(p.y, q.y);
        float yy2 = fminf(p.z, q.z);
        float xx2 = fminf(p.w, q.w);
        float inter = fmaxf(yy2 - yy1, 0.f) * fmaxf(xx2 - xx1, 0.f);
        float denom = ((pa + qa) - inter) + EPS_F;
        bool sup = ((double)inter > M_D * (double)denom) && (c > r);
        ull m = __ballot(sup ? 1 : 0);
        if (lane == 0) row[k] = m;
    }
}

// ---------------------------------------------------------------------------
// Kernel F: word-walk greedy scan, one wave per batch. All mask logic is
// SCALARIZED (readlane -> uniform) so row-load batches are unconditional and
// stay resident in VGPRs -> full memory-level parallelism per word.
// __launch_bounds__(64,1): allow ~high VGPR use (grid is 8 waves total).
// ---------------------------------------------------------------------------
__global__ __launch_bounds__(64, 1)
void nms_scan_kernel(const float4* __restrict__ boxes_ws,
                     const ull* __restrict__ alive_ws,
                     const ull* __restrict__ mat,
                     float* __restrict__ out)
{
    const int b    = blockIdx.x;
    const int lane = threadIdx.x;

    __shared__ int picks[PROP];

    // lane l (<48) holds alive words 2l, 2l+1 (words 94,95 zero by construction)
    ull aw0 = 0, aw1 = 0;
    if (lane < 48) {
        const ull* aw = alive_ws + (size_t)b * MROW + 2 * lane;
        aw0 = aw[0]; aw1 = aw[1];
    }

    const ull* mb = mat + (size_t)b * PRE_NMS * MROW;
    // diag for word 0: lane i -> mat[i][word 0]
    ull diag = mb[(size_t)lane * MROW];
    int cnt = 0;

    for (int k = 0; k < 94; ++k) {
        // ---- alive word k as a uniform (scalar) value
        const int src = k >> 1;
        const ull awk = (k & 1) ? aw1 : aw0;
        u32 wlo = (u32)__builtin_amdgcn_readlane((int)(u32)awk, src);
        u32 whi = (u32)__builtin_amdgcn_readlane((int)(u32)(awk >> 32), src);
        ull wval = ((ull)whi << 32) | (ull)wlo;

        ull diag_cur = diag;
        if (k < 93) {                                     // prefetch word k+1 diagonal
            int r = ((k + 1) << 6) + lane;
            diag = (r < PRE_NMS) ? mb[(size_t)r * MROW + (k + 1)] : 0ull;
        }
        if (wval == 0ull) continue;

        // ---- resolve picks within word k (fully scalar)
        ull m = wval;
        ull pickedm = 0ull;
        while (m) {
            int p = __ffsll(m) - 1;                       // uniform
            u32 lo = (u32)__builtin_amdgcn_readlane((int)(u32)diag_cur, p);
            u32 hi = (u32)__builtin_amdgcn_readlane((int)(u32)(diag_cur >> 32), p);
            ull sup = ((ull)hi << 32) | (ull)lo;          // word-k bits suppressed by pick p
            if (lane == 0) picks[cnt] = (k << 6) + p;
            ++cnt;
            pickedm |= (1ull << p);
            m &= ~(sup | (1ull << p));
            if (cnt == PROP) break;
        }

        // ---- OR picked rows into alive regs; 16 unconditional loads per batch
        ull t = pickedm;                                  // uniform
        while (t) {
            int  rowid[16];
            bool vld[16];
            #pragma unroll
            for (int g = 0; g < 16; ++g) {
                if (t) {
                    int p = __ffsll(t) - 1;
                    t &= t - 1ull;
                    rowid[g] = (k << 6) + p;
                    vld[g] = true;
                } else {
                    rowid[g] = 0;                          // harmless dummy row
                    vld[g] = false;
                }
            }
            ull vx[16], vy[16];
            if (lane < 48) {
                #pragma unroll
                for (int g = 0; g < 16; ++g) {
                    const ulonglong2* rp =
                        reinterpret_cast<const ulonglong2*>(mb + (size_t)rowid[g] * MROW) + lane;
                    ulonglong2 v = *rp;
                    vx[g] = v.x; vy[g] = v.y;
                }
            } else {
                #pragma unroll
                for (int g = 0; g < 16; ++g) { vx[g] = 0; vy[g] = 0; }
            }
            ull rx = 0, ry = 0;
            #pragma unroll
            for (int g = 0; g < 16; ++g) {
                if (vld[g]) { rx |= vx[g]; ry |= vy[g]; }  // scalar branch
            }
            aw0 &= ~rx; aw1 &= ~ry;
        }
        // word k fully consumed
        if (lane == (k >> 1)) { if (k & 1) aw1 = 0ull; else aw0 = 0ull; }
        if (cnt == PROP) break;
    }

    __syncthreads();
    const float4* bws = boxes_ws + (size_t)b * NSLOT;
    float4* ob = reinterpret_cast<float4*>(out + (size_t)b * PROP * 4);
    for (int i = lane; i < PROP; i += 64) {
        float4 v = make_float4(0.f, 0.f, 0.f, 0.f);
        if (i < cnt) v = bws[picks[i]];
        ob[i] = v;
    }
}

// ---------------------------------------------------------------------------
// Fallback: round-1 monolithic kernel (used if ws too small). Verified exact.
// ---------------------------------------------------------------------------
__device__ __forceinline__ void hist_add_f(unsigned int* hist, unsigned int bin, bool valid) {
    const int lane = threadIdx.x & 63;
    ull todo = __ballot(valid ? 1 : 0);
    #pragma unroll
    for (int it = 0; it < 3; ++it) {
        if (!todo) return;
        int leader = __ffsll(todo) - 1;
        unsigned int lbin = __shfl(bin, leader);
        ull grp = __ballot((valid && (bin == lbin)) ? 1 : 0);
        if (lane == leader) atomicAdd(&hist[lbin], (unsigned int)__popcll(grp));
        todo &= ~grp;
    }
    if ((todo >> lane) & 1ull) atomicAdd(&hist[bin], 1u);
}

__global__ __launch_bounds__(1024)
void proposal_fallback(const float* __restrict__ rpn_probs,
                       const float* __restrict__ rpn_bbox,
                       const float* __restrict__ anchors,
                       float* __restrict__ out)
{
    const int b    = blockIdx.x;
    const int t    = threadIdx.x;
    const int lane = t & 63;
    const int wv   = t >> 6;

    const float2* __restrict__ probs2 = reinterpret_cast<const float2*>(rpn_probs + (size_t)b * NANCH * 2);
    const float4* __restrict__ bbox4  = reinterpret_cast<const float4*>(rpn_bbox  + (size_t)b * NANCH * 4);
    const float4* __restrict__ anc4   = reinterpret_cast<const float4*>(anchors   + (size_t)b * NANCH * 4);
    float* __restrict__ outb = out + (size_t)b * PROP * 4;

    __shared__ __align__(16) char s_big[NSLOT * 16];
    __shared__ ull          s_alive[96];
    __shared__ unsigned int s_hist[256];
    __shared__ unsigned int s_pref;
    __shared__ unsigned int s_targ;
    __shared__ unsigned int s_cnt;

    ull*    sel   = reinterpret_cast<ull*>(s_big);
    float4* boxes = reinterpret_cast<float4*>(s_big);

    const int ITER = (NANCH + 1023) >> 10;

    if (t == 0) { s_pref = 0u; s_targ = PRE_NMS; s_cnt = 0u; }

    for (int p = 0; p < 4; ++p) {
        if (t < 256) s_hist[t] = 0u;
        __syncthreads();
        const unsigned int pref  = s_pref;
        const int          shift = 8 * (3 - p);
        const unsigned int pmask = (p == 0) ? 0u : (0xFFFFFFFFu << (shift + 8));
        for (int i = 0; i < ITER; ++i) {
            int  n     = (i << 10) + t;
            bool valid = (n < NANCH);
            unsigned int key = 0u;
            if (valid) key = __float_as_uint(probs2[n].y);
            bool match = valid && ((key & pmask) == (pref & pmask));
            hist_add_f(s_hist, (key >> shift) & 0xFFu, match);
        }
        __syncthreads();
        if (t == 0) {
            unsigned int target = s_targ;
            unsigned int acc = 0u;
            int v = 255;
            for (; v >= 0; --v) {
                unsigned int h = s_hist[v];
                if (acc + h >= target) break;
                acc += h;
            }
            if (v < 0) v = 0;
            s_pref = pref | ((unsigned int)v << shift);
            s_targ = target - acc;
        }
        __syncthreads();
    }

    const unsigned int T = s_pref;
    __syncthreads();

    for (int i = 0; i < ITER; ++i) {
        int  n     = (i << 10) + t;
        bool valid = (n < NANCH);
        unsigned int key = 0u;
        if (valid) key = __float_as_uint(probs2[n].y);
        bool selp = valid && (key >= T);
        ull  m    = __ballot(selp ? 1 : 0);
        if (m) {
            int leader = __ffsll(m) - 1;
            unsigned int base = 0u;
            if (lane == leader) base = atomicAdd(&s_cnt, (unsigned int)__popcll(m));
            base = __shfl(base, leader);
            if (selp) {
                unsigned int off = base + (unsigned int)__popcll(m & ((1ull << lane) - 1ull));
                if (off < SORTN) sel[off] = ((ull)(~key) << 32) | (ull)(unsigned int)n;
            }
        }
    }
    __syncthreads();
    const unsigned int C = s_cnt;
    for (int s = (int)C + t; s < SORTN; s += 1024) sel[s] = ~0ull;
    __syncthreads();

    for (unsigned int k = 2; k <= SORTN; k <<= 1) {
        for (unsigned int j = k >> 1; j > 0; j >>= 1) {
            #pragma unroll
            for (int r = 0; r < SORTN / 1024; ++r) {
                int i = (r << 10) + t;
                int l = i ^ (int)j;
                if (l > i) {
                    ull a  = sel[i];
                    ull bq = sel[l];
                    bool up = ((i & (int)k) == 0);
                    if ((a > bq) == up) { sel[i] = bq; sel[l] = a; }
                }
            }
            __syncthreads();
        }
    }

    ull ss[6];
    #pragma unroll
    for (int e = 0; e < 6; ++e) ss[e] = sel[(e << 10) + t];
    __syncthreads();

    float4 rbox[6];
    float  rarea[6];
    #pragma unroll
    for (int e = 0; e < 6; ++e) {
        int s = (e << 10) + t;
        float4 bx = make_float4(0.f, 0.f, 0.f, 0.f);
        bool ok = false;
        if (s < PRE_NMS) {
            unsigned int key = ~(unsigned int)(ss[e] >> 32);
            unsigned int n   = (unsigned int)(ss[e] & 0xFFFFFFFFull);
            float4 a = anc4[n];
            float4 d = bbox4[n];
            float dy = d.x * 0.1f, dx = d.y * 0.1f, dh = d.z * 0.2f, dw = d.w * 0.2f;
            float h  = a.z - a.x;
            float w  = a.w - a.y;
            float cy = a.x + 0.5f * h;
            float cx = a.y + 0.5f * w;
            cy = cy + dy * h;
            cx = cx + dx * w;
            h  = h * expf(dh);
            w  = w * expf(dw);
            float y1 = cy - 0.5f * h;
            float x1 = cx - 0.5f * w;
            float y2 = y1 + h;
            float x2 = x1 + w;
            y1 = fminf(fmaxf(y1, 0.f), 1.f);
            x1 = fminf(fmaxf(x1, 0.f), 1.f);
            y2 = fminf(fmaxf(y2, 0.f), 1.f);
            x2 = fminf(fmaxf(x2, 0.f), 1.f);
            bx = make_float4(y1, x1, y2, x2);
            ok = (key >= SCORE_THRES_BITS);
        }
        rbox[e]  = bx;
        rarea[e] = (bx.z - bx.x) * (bx.w - bx.y);
        boxes[s] = bx;
        ull am = __ballot(ok ? 1 : 0);
        if (lane == 0) s_alive[wv + (e << 4)] = am;
    }

    int emitted = 0;
    for (;;) {
        __syncthreads();
        if (emitted == PROP) break;
        ull w0 = s_alive[lane];
        ull w1 = (lane < 32) ? s_alive[64 + lane] : 0ull;
        ull nz0 = __ballot(w0 != 0ull ? 1 : 0);
        ull nz1 = __ballot(w1 != 0ull ? 1 : 0);
        int pick = -1;
        if (nz0) {
            int wd = __ffsll(nz0) - 1;
            ull wvv = __shfl(w0, wd);
            pick = (wd << 6) + __ffsll(wvv) - 1;
        } else if (nz1) {
            int wd = __ffsll(nz1) - 1;
            ull wvv = __shfl(w1, wd);
            pick = ((wd + 64) << 6) + __ffsll(wvv) - 1;
        }
        if (pick < 0) break;
        __syncthreads();

        if (t < 4) outb[(emitted << 2) + t] = reinterpret_cast<const float*>(s_big)[(pick << 2) + t];

        float4 p = boxes[pick];
        float parea = (p.z - p.x) * (p.w - p.y);
        #pragma unroll
        for (int e = 0; e < 6; ++e) {
            float4 bb  = rbox[e];
            float yy1 = fmaxf(p.x, bb.x);
            float xx1 = fmaxf(p.y, bb.y);
            float yy2 = fminf(p.z, bb.z);
            float xx2 = fminf(p.w, bb.w);
            float ih  = fmaxf(yy2 - yy1, 0.f);
            float iw  = fmaxf(xx2 - xx1, 0.f);
            float inter = ih * iw;
            float denom = ((parea + rarea[e]) - inter) + EPS_F;
            bool  sup   = ((double)inter > M_D * (double)denom);
            ull m = __ballot(sup ? 1 : 0);
            int word = wv + (e << 4);
            if (word == (pick >> 6)) m |= (1ull << (pick & 63));
            if (lane == 0) s_alive[word] &= ~m;
        }
        ++emitted;
    }

    for (int i = (emitted << 2) + t; i < PROP * 4; i += 1024) outb[i] = 0.f;
}

extern "C" void kernel_launch(void* const* d_in, const int* in_sizes, int n_in,
                              void* d_out, int out_size, void* d_ws, size_t ws_size,
                              hipStream_t stream) {
    const float* rpn_probs = (const float*)d_in[0];
    const float* rpn_bbox  = (const float*)d_in[1];
    const float* anchors   = (const float*)d_in[2];
    float* out = (float*)d_out;

    // ws layout (low MiB): boxes | alive | misc(Tc, cnt8). [1MiB..): mat.
    // ghist + selbuf live INSIDE the mat region EXCEPT selbuf, which is read by
    // rank_decode AFTER... careful: rank_decode runs before iou_matrix writes mat,
    // so overlap is safe (selbuf fully consumed before mat is produced).
    const size_t BOX_OFF   = 0;
    const size_t ALIVE_OFF = (size_t)BATCH * NSLOT * sizeof(float4);           // 786432
    const size_t MISC_OFF  = 832 * 1024;                                       // Tc[8], cnt8[8]
    const size_t MAT_OFF   = 1u << 20;
    const size_t GHIST_OFF = MAT_OFF;                                          // 8*16384*4 = 512 KB
    const size_t SELB_OFF  = MAT_OFF + (size_t)BATCH * NBIN * 4;               // 8*8192*8 = 512 KB
    const size_t WS_NEED   = MAT_OFF + (size_t)BATCH * PRE_NMS * MROW * 8;     // ~37.9 MB

    if (d_ws != nullptr && ws_size >= WS_NEED) {
        char* ws = (char*)d_ws;
        float4* boxes_ws = (float4*)(ws + BOX_OFF);
        ull*    alive_ws = (ull*)(ws + ALIVE_OFF);
        u32*    Tc       = (u32*)(ws + MISC_OFF);
        u32*    cnt8     = (u32*)(ws + MISC_OFF + 64);
        u32*    ghist    = (u32*)(ws + GHIST_OFF);
        ull*    selbuf   = (ull*)(ws + SELB_OFF);
        ull*    mat      = (ull*)(ws + MAT_OFF);

        hipMemsetAsync(ghist, 0, (size_t)BATCH * NBIN * 4, stream);
        hipMemsetAsync(cnt8, 0, 64, stream);
        hipMemsetAsync(alive_ws, 0, (size_t)BATCH * MROW * 8, stream);
        hipLaunchKernelGGL(hist_kernel, dim3(64, BATCH), dim3(256), 0, stream,
                           rpn_probs, ghist);
        hipLaunchKernelGGL(findT_kernel, dim3(BATCH), dim3(1024), 0, stream,
                           ghist, Tc);
        hipLaunchKernelGGL(compact_kernel, dim3(64, BATCH), dim3(256), 0, stream,
                           rpn_probs, Tc, selbuf, cnt8);
        hipLaunchKernelGGL(rank_decode_kernel, dim3(SORTN / 256, BATCH), dim3(256), 0, stream,
                           rpn_bbox, anchors, selbuf, cnt8, boxes_ws, alive_ws);
        hipLaunchKernelGGL(iou_matrix_kernel, dim3(PRE_NMS / 16, BATCH), dim3(1024), 0, stream,
                           boxes_ws, mat);
        hipLaunchKernelGGL(nms_scan_kernel, dim3(BATCH), dim3(64), 0, stream,
                           boxes_ws, alive_ws, mat, out);
    } else {
        hipLaunchKernelGGL(proposal_fallback, dim3(BATCH), dim3(1024), 0, stream,
                           rpn_probs, rpn_bbox, anchors, out);
    }
}

// Round 6
// 507.149 us; speedup vs baseline: 4.5922x; 1.6030x over previous
//
#include <hip/hip_runtime.h>
#include <cstdint>
#include <cstddef>

#pragma clang fp contract(off)

#define BATCH    8
#define NANCH    261888
#define PRE_NMS  6000
#define PROP     1000
#define SORTN    8192
#define NSLOT    6144          /* 6 * 1024 */
#define MROW     96            /* u64 words per suppression row (94 used + 2 pad) */
#define NPAIR    130944        /* NANCH / 2 */
#define CBLK     32            /* blocks per batch for hist/compact */
#define CPAIR    4092          /* NPAIR / CBLK */
#define KCAP     1024          /* compact LDS staging capacity (mean ~210, +57 sigma) */
#define SCORE_THRES_BITS 0x3F000000u   /* bits of 0.5f */
#define EPS_F    1e-8f
/* midpoint between pred(0.7f) and 0.7f = 23488101 * 2^-25, exact in double.
   RN(inter/denom) >= 0.7f  <=>  inter > M_D * denom  (exact: 25b x 24b product). */
#define M_D      0.6999999582767486572265625

typedef unsigned long long ull;
typedef unsigned int u32;

// ---------------------------------------------------------------------------
// Kernel A: fine histogram of scores >= 0.5 into 129 bins (16-bit-prefix bin
// boundaries: bin i = keys [0x3F000000+(i<<16), +0x10000), bin 128 = key
// >= 0x3F800000). The 6000th score is >= 0.5 w.p. 1 (131k of 262k scores are
// >= 0.5), so these bins always contain the threshold. grid (32,B) x 256.
// ---------------------------------------------------------------------------
__global__ __launch_bounds__(256)
void hist_kernel(const float* __restrict__ rpn_probs, u32* __restrict__ ghist)
{
    __shared__ u32 h[129];
    const int t = threadIdx.x;
    const int b = blockIdx.y;
    if (t < 129) h[t] = 0u;
    __syncthreads();

    const float4* p4 = reinterpret_cast<const float4*>(rpn_probs + (size_t)b * NANCH * 2);
    const int p0 = blockIdx.x * CPAIR;
    for (int i = t; i < CPAIR; i += 256) {
        float4 v = p4[p0 + i];                 // scores of anchors 2p, 2p+1 in .y/.w
        u32 k0 = __float_as_uint(v.y);
        u32 k1 = __float_as_uint(v.w);
        if (k0 >= 0x3F000000u) atomicAdd(&h[min((k0 >> 16) - 0x3F00u, 128u)], 1u);
        if (k1 >= 0x3F000000u) atomicAdd(&h[min((k1 >> 16) - 0x3F00u, 128u)], 1u);
    }
    __syncthreads();
    if (t < 129 && h[t]) atomicAdd(&ghist[(b << 8) + t], h[t]);
}

// ---------------------------------------------------------------------------
// Kernel B: coarse threshold = start of the bin containing the 6000th score.
// grid (BATCH) x 64.
// ---------------------------------------------------------------------------
__global__ __launch_bounds__(64)
void findT_kernel(const u32* __restrict__ ghist, u32* __restrict__ Tc)
{
    __shared__ u32 h[129];
    const int b = blockIdx.x;
    const int t = threadIdx.x;
    for (int j = t; j < 129; j += 64) h[j] = ghist[(b << 8) + j];
    __syncthreads();
    if (t == 0) {
        u32 run = 0; int bin = -1;
        for (int i = 128; i >= 0; --i) {
            run += h[i];
            if (run >= PRE_NMS) { bin = i; break; }
        }
        u32 T;
        if (bin < 0)        T = 0x3F000000u;        // unreachable (131k scores >= 0.5)
        else if (bin == 128) T = 0x3F800000u;
        else                 T = 0x3F000000u + ((u32)bin << 16);
        Tc[b] = T;
    }
}

// ---------------------------------------------------------------------------
// Kernel C: compact keys >= Tc[b] into selbuf. Block-local LDS staging +
// ONE padded global atomic per block (fixes the R4 301us single-cacheline
// atomic pileup). Spill path is exact (statistically unreachable).
// grid (32, BATCH) x 256. cntp stride: 64 u32 (256 B) per batch.
// ---------------------------------------------------------------------------
__global__ __launch_bounds__(256)
void compact_kernel(const float* __restrict__ rpn_probs,
                    const u32* __restrict__ Tc,
                    ull* __restrict__ selbuf, u32* __restrict__ cntp)
{
    __shared__ ull kbuf[KCAP];
    __shared__ u32 s_n;
    __shared__ u32 s_base;
    const int t    = threadIdx.x;
    const int lane = t & 63;
    const int b    = blockIdx.y;
    const u32 T = Tc[b];
    if (t == 0) s_n = 0u;
    __syncthreads();

    const float4* p4 = reinterpret_cast<const float4*>(rpn_probs + (size_t)b * NANCH * 2);
    ull* sb = selbuf + (size_t)b * SORTN;
    const int p0 = blockIdx.x * CPAIR;

    for (int i = t; i < CPAIR; i += 256) {
        float4 v = p4[p0 + i];
        const int n0 = (p0 + i) << 1;
        #pragma unroll
        for (int e = 0; e < 2; ++e) {
            u32 k = __float_as_uint(e ? v.w : v.y);
            bool s0 = (k >= T);
            ull m = __ballot(s0 ? 1 : 0);
            if (!m) continue;                                  // wave-uniform
            int ldr = __ffsll(m) - 1;
            u32 base = 0;
            if (lane == ldr) base = atomicAdd(&s_n, (u32)__popcll(m));
            base = __shfl(base, ldr);
            u32 off = base + (u32)__popcll(m & ((1ull << lane) - 1ull));
            bool fit = s0 && (off < KCAP);
            if (fit) kbuf[off] = ((ull)(~k) << 32) | (ull)(u32)(n0 + e);
            ull sp = __ballot((s0 && !fit) ? 1 : 0);           // exact spill (unreachable)
            if (sp) {
                int l2 = __ffsll(sp) - 1;
                u32 gb = 0;
                if (lane == l2) gb = atomicAdd(&cntp[b << 6], (u32)__popcll(sp));
                gb = __shfl(gb, l2);
                if (s0 && !fit) {
                    u32 go = gb + (u32)__popcll(sp & ((1ull << lane) - 1ull));
                    if (go < SORTN) sb[go] = ((ull)(~k) << 32) | (ull)(u32)(n0 + e);
                }
            }
        }
    }
    __syncthreads();
    const u32 nn = min(s_n, (u32)KCAP);
    if (t == 0) s_base = atomicAdd(&cntp[b << 6], nn);
    __syncthreads();
    const u32 bs = s_base;
    for (u32 j = t; j < nn; j += 256) {
        u32 off = bs + j;
        if (off < SORTN) sb[off] = kbuf[j];
    }
}

// ---------------------------------------------------------------------------
// Kernel D: rank-scatter. slot(i) = #{j : comp_j < comp_i} — identical to
// ascending sort of the unique composite keys. Decode + scatter + alive
// atomicOr fused. grid (32, BATCH) x 256; LDS-tiled comparison corpus.
// ---------------------------------------------------------------------------
__global__ __launch_bounds__(256)
void rank_decode_kernel(const float* __restrict__ rpn_bbox,
                        const float* __restrict__ anchors,
                        const ull* __restrict__ selbuf,
                        const u32* __restrict__ cntp,
                        float4* __restrict__ boxes_ws,
                        ull* __restrict__ alive_ws)
{
    __shared__ ull tile[2048];   // 16 KB
    const int t = threadIdx.x;
    const int b = blockIdx.y;
    const u32 C = min(cntp[b << 6], (u32)SORTN);
    const ull* sb = selbuf + (size_t)b * SORTN;

    const int i = (blockIdx.x << 8) + t;
    const ull mykey = (i < (int)C) ? sb[i] : ~0ull;

    int rank = 0;
    for (u32 tb = 0; tb < C; tb += 2048) {
        const int m = (int)min((u32)2048, C - tb);
        __syncthreads();
        for (int j = t; j < m; j += 256) tile[j] = sb[tb + j];
        __syncthreads();
        int j = 0;
        for (; j + 8 <= m; j += 8) {
            #pragma unroll
            for (int u = 0; u < 8; ++u) rank += (tile[j + u] < mykey) ? 1 : 0;
        }
        for (; j < m; ++j) rank += (tile[j] < mykey) ? 1 : 0;
    }

    if (i < (int)C && rank < PRE_NMS) {
        const u32 key = ~(u32)(mykey >> 32);
        const u32 n   = (u32)(mykey & 0xFFFFFFFFull);
        const float4* bbox4 = reinterpret_cast<const float4*>(rpn_bbox + (size_t)b * NANCH * 4);
        const float4* anc4  = reinterpret_cast<const float4*>(anchors  + (size_t)b * NANCH * 4);
        float4 a = anc4[n];
        float4 d = bbox4[n];
        float dy = d.x * 0.1f, dx = d.y * 0.1f, dh = d.z * 0.2f, dw = d.w * 0.2f;
        float h  = a.z - a.x;
        float w  = a.w - a.y;
        float cy = a.x + 0.5f * h;
        float cx = a.y + 0.5f * w;
        cy = cy + dy * h;
        cx = cx + dx * w;
        h  = h * expf(dh);
        w  = w * expf(dw);
        float y1 = cy - 0.5f * h;
        float x1 = cx - 0.5f * w;
        float y2 = y1 + h;
        float x2 = x1 + w;
        y1 = fminf(fmaxf(y1, 0.f), 1.f);
        x1 = fminf(fmaxf(x1, 0.f), 1.f);
        y2 = fminf(fmaxf(y2, 0.f), 1.f);
        x2 = fminf(fmaxf(x2, 0.f), 1.f);
        boxes_ws[(size_t)b * NSLOT + rank] = make_float4(y1, x1, y2, x2);
        if (key >= SCORE_THRES_BITS) {
            atomicOr(&alive_ws[(size_t)b * MROW + (rank >> 6)], 1ull << (rank & 63));
        }
    }
}

// ---------------------------------------------------------------------------
// Kernel E: suppression bit-matrix. Row r, bit j set iff j>r and IoU>=0.7.
// grid (375, BATCH) x 1024 (16 waves -> 16 rows/block).
// ---------------------------------------------------------------------------
__global__ __launch_bounds__(1024)
void iou_matrix_kernel(const float4* __restrict__ boxes_ws,
                       ull* __restrict__ mat)
{
    __shared__ float4 sbox[NSLOT];   // 96 KB
    const int b    = blockIdx.y;
    const int t    = threadIdx.x;
    const int lane = t & 63;
    const int wv   = t >> 6;

    const float4* bws = boxes_ws + (size_t)b * NSLOT;
    #pragma unroll
    for (int i = 0; i < 6; ++i) sbox[(i << 10) + t] = bws[(i << 10) + t];
    __syncthreads();

    const int r = (blockIdx.x << 4) + wv;
    if (r >= PRE_NMS) return;

    float4 p = sbox[r];
    float pa = (p.z - p.x) * (p.w - p.y);
    ull* row = mat + ((size_t)b * PRE_NMS + r) * MROW;

    const int k0 = r >> 6;
    for (int w = lane; w < k0; w += 64) row[w] = 0;
    if (lane < 2) row[94 + lane] = 0;

    for (int k = k0; k < 94; ++k) {
        int c = (k << 6) + lane;
        float4 q = sbox[c];
        float qa  = (q.z - q.x) * (q.w - q.y);
        float yy1 = fmaxf(p.x, q.x);
        float xx1 = fmaxf(p.y, q.y);
        float yy2 = fminf(p.z, q.z);
        float xx2 = fminf(p.w, q.w);
        float inter = fmaxf(yy2 - yy1, 0.f) * fmaxf(xx2 - xx1, 0.f);
        float denom = ((pa + qa) - inter) + EPS_F;
        bool sup = ((double)inter > M_D * (double)denom) && (c > r);
        ull m = __ballot(sup ? 1 : 0);
        if (lane == 0) row[k] = m;
    }
}

// ---------------------------------------------------------------------------
// Kernel F: word-walk greedy scan, one wave per batch. All mask logic is
// SCALARIZED (readlane -> uniform) so row-load batches are unconditional and
// stay resident in VGPRs -> full memory-level parallelism per word.
// __launch_bounds__(64,1): allow high VGPR use (grid is 8 waves total).
// ---------------------------------------------------------------------------
__global__ __launch_bounds__(64, 1)
void nms_scan_kernel(const float4* __restrict__ boxes_ws,
                     const ull* __restrict__ alive_ws,
                     const ull* __restrict__ mat,
                     float* __restrict__ out)
{
    const int b    = blockIdx.x;
    const int lane = threadIdx.x;

    __shared__ int picks[PROP];

    // lane l (<48) holds alive words 2l, 2l+1 (words 94,95 zero by construction)
    ull aw0 = 0, aw1 = 0;
    if (lane < 48) {
        const ull* aw = alive_ws + (size_t)b * MROW + 2 * lane;
        aw0 = aw[0]; aw1 = aw[1];
    }

    const ull* mb = mat + (size_t)b * PRE_NMS * MROW;
    // diag for word 0: lane i -> mat[i][word 0]
    ull diag = mb[(size_t)lane * MROW];
    int cnt = 0;

    for (int k = 0; k < 94; ++k) {
        // ---- alive word k as a uniform (scalar) value
        const int src = k >> 1;
        const ull awk = (k & 1) ? aw1 : aw0;
        u32 wlo = (u32)__builtin_amdgcn_readlane((int)(u32)awk, src);
        u32 whi = (u32)__builtin_amdgcn_readlane((int)(u32)(awk >> 32), src);
        ull wval = ((ull)whi << 32) | (ull)wlo;

        ull diag_cur = diag;
        if (k < 93) {                                     // prefetch word k+1 diagonal
            int r = ((k + 1) << 6) + lane;
            diag = (r < PRE_NMS) ? mb[(size_t)r * MROW + (k + 1)] : 0ull;
        }
        if (wval == 0ull) continue;

        // ---- resolve picks within word k (fully scalar)
        ull m = wval;
        ull pickedm = 0ull;
        while (m) {
            int p = __ffsll(m) - 1;                       // uniform
            u32 lo = (u32)__builtin_amdgcn_readlane((int)(u32)diag_cur, p);
            u32 hi = (u32)__builtin_amdgcn_readlane((int)(u32)(diag_cur >> 32), p);
            ull sup = ((ull)hi << 32) | (ull)lo;          // word-k bits suppressed by pick p
            if (lane == 0) picks[cnt] = (k << 6) + p;
            ++cnt;
            pickedm |= (1ull << p);
            m &= ~(sup | (1ull << p));
            if (cnt == PROP) break;
        }

        // ---- OR picked rows into alive regs; 16 unconditional loads per batch
        ull t = pickedm;                                  // uniform
        while (t) {
            int  rowid[16];
            bool vld[16];
            #pragma unroll
            for (int g = 0; g < 16; ++g) {
                if (t) {
                    int p = __ffsll(t) - 1;
                    t &= t - 1ull;
                    rowid[g] = (k << 6) + p;
                    vld[g] = true;
                } else {
                    rowid[g] = 0;                          // harmless dummy row
                    vld[g] = false;
                }
            }
            ull vx[16], vy[16];
            if (lane < 48) {
                #pragma unroll
                for (int g = 0; g < 16; ++g) {
                    const ulonglong2* rp =
                        reinterpret_cast<const ulonglong2*>(mb + (size_t)rowid[g] * MROW) + lane;
                    ulonglong2 v = *rp;
                    vx[g] = v.x; vy[g] = v.y;
                }
            } else {
                #pragma unroll
                for (int g = 0; g < 16; ++g) { vx[g] = 0; vy[g] = 0; }
            }
            ull rx = 0, ry = 0;
            #pragma unroll
            for (int g = 0; g < 16; ++g) {
                if (vld[g]) { rx |= vx[g]; ry |= vy[g]; }  // scalar branch
            }
            aw0 &= ~rx; aw1 &= ~ry;
        }
        // word k fully consumed
        if (lane == (k >> 1)) { if (k & 1) aw1 = 0ull; else aw0 = 0ull; }
        if (cnt == PROP) break;
    }

    __syncthreads();
    const float4* bws = boxes_ws + (size_t)b * NSLOT;
    float4* ob = reinterpret_cast<float4*>(out + (size_t)b * PROP * 4);
    for (int i = lane; i < PROP; i += 64) {
        float4 v = make_float4(0.f, 0.f, 0.f, 0.f);
        if (i < cnt) v = bws[picks[i]];
        ob[i] = v;
    }
}

// ---------------------------------------------------------------------------
// Fallback: round-1 monolithic kernel (used if ws too small). Verified exact.
// ---------------------------------------------------------------------------
__device__ __forceinline__ void hist_add_f(unsigned int* hist, unsigned int bin, bool valid) {
    const int lane = threadIdx.x & 63;
    ull todo = __ballot(valid ? 1 : 0);
    #pragma unroll
    for (int it = 0; it < 3; ++it) {
        if (!todo) return;
        int leader = __ffsll(todo) - 1;
        unsigned int lbin = __shfl(bin, leader);
        ull grp = __ballot((valid && (bin == lbin)) ? 1 : 0);
        if (lane == leader) atomicAdd(&hist[lbin], (unsigned int)__popcll(grp));
        todo &= ~grp;
    }
    if ((todo >> lane) & 1ull) atomicAdd(&hist[bin], 1u);
}

__global__ __launch_bounds__(1024)
void proposal_fallback(const float* __restrict__ rpn_probs,
                       const float* __restrict__ rpn_bbox,
                       const float* __restrict__ anchors,
                       float* __restrict__ out)
{
    const int b    = blockIdx.x;
    const int t    = threadIdx.x;
    const int lane = t & 63;
    const int wv   = t >> 6;

    const float2* __restrict__ probs2 = reinterpret_cast<const float2*>(rpn_probs + (size_t)b * NANCH * 2);
    const float4* __restrict__ bbox4  = reinterpret_cast<const float4*>(rpn_bbox  + (size_t)b * NANCH * 4);
    const float4* __restrict__ anc4   = reinterpret_cast<const float4*>(anchors   + (size_t)b * NANCH * 4);
    float* __restrict__ outb = out + (size_t)b * PROP * 4;

    __shared__ __align__(16) char s_big[NSLOT * 16];
    __shared__ ull          s_alive[96];
    __shared__ unsigned int s_hist[256];
    __shared__ unsigned int s_pref;
    __shared__ unsigned int s_targ;
    __shared__ unsigned int s_cnt;

    ull*    sel   = reinterpret_cast<ull*>(s_big);
    float4* boxes = reinterpret_cast<float4*>(s_big);

    const int ITER = (NANCH + 1023) >> 10;

    if (t == 0) { s_pref = 0u; s_targ = PRE_NMS; s_cnt = 0u; }

    for (int p = 0; p < 4; ++p) {
        if (t < 256) s_hist[t] = 0u;
        __syncthreads();
        const unsigned int pref  = s_pref;
        const int          shift = 8 * (3 - p);
        const unsigned int pmask = (p == 0) ? 0u : (0xFFFFFFFFu << (shift + 8));
        for (int i = 0; i < ITER; ++i) {
            int  n     = (i << 10) + t;
            bool valid = (n < NANCH);
            unsigned int key = 0u;
            if (valid) key = __float_as_uint(probs2[n].y);
            bool match = valid && ((key & pmask) == (pref & pmask));
            hist_add_f(s_hist, (key >> shift) & 0xFFu, match);
        }
        __syncthreads();
        if (t == 0) {
            unsigned int target = s_targ;
            unsigned int acc = 0u;
            int v = 255;
            for (; v >= 0; --v) {
                unsigned int h = s_hist[v];
                if (acc + h >= target) break;
                acc += h;
            }
            if (v < 0) v = 0;
            s_pref = pref | ((unsigned int)v << shift);
            s_targ = target - acc;
        }
        __syncthreads();
    }

    const unsigned int T = s_pref;
    __syncthreads();

    for (int i = 0; i < ITER; ++i) {
        int  n     = (i << 10) + t;
        bool valid = (n < NANCH);
        unsigned int key = 0u;
        if (valid) key = __float_as_uint(probs2[n].y);
        bool selp = valid && (key >= T);
        ull  m    = __ballot(selp ? 1 : 0);
        if (m) {
            int leader = __ffsll(m) - 1;
            unsigned int base = 0u;
            if (lane == leader) base = atomicAdd(&s_cnt, (unsigned int)__popcll(m));
            base = __shfl(base, leader);
            if (selp) {
                unsigned int off = base + (unsigned int)__popcll(m & ((1ull << lane) - 1ull));
                if (off < SORTN) sel[off] = ((ull)(~key) << 32) | (ull)(unsigned int)n;
            }
        }
    }
    __syncthreads();
    const unsigned int C = s_cnt;
    for (int s = (int)C + t; s < SORTN; s += 1024) sel[s] = ~0ull;
    __syncthreads();

    for (unsigned int k = 2; k <= SORTN; k <<= 1) {
        for (unsigned int j = k >> 1; j > 0; j >>= 1) {
            #pragma unroll
            for (int r = 0; r < SORTN / 1024; ++r) {
                int i = (r << 10) + t;
                int l = i ^ (int)j;
                if (l > i) {
                    ull a  = sel[i];
                    ull bq = sel[l];
                    bool up = ((i & (int)k) == 0);
                    if ((a > bq) == up) { sel[i] = bq; sel[l] = a; }
                }
            }
            __syncthreads();
        }
    }

    ull ss[6];
    #pragma unroll
    for (int e = 0; e < 6; ++e) ss[e] = sel[(e << 10) + t];
    __syncthreads();

    float4 rbox[6];
    float  rarea[6];
    #pragma unroll
    for (int e = 0; e < 6; ++e) {
        int s = (e << 10) + t;
        float4 bx = make_float4(0.f, 0.f, 0.f, 0.f);
        bool ok = false;
        if (s < PRE_NMS) {
            unsigned int key = ~(unsigned int)(ss[e] >> 32);
            unsigned int n   = (unsigned int)(ss[e] & 0xFFFFFFFFull);
            float4 a = anc4[n];
            float4 d = bbox4[n];
            float dy = d.x * 0.1f, dx = d.y * 0.1f, dh = d.z * 0.2f, dw = d.w * 0.2f;
            float h  = a.z - a.x;
            float w  = a.w - a.y;
            float cy = a.x + 0.5f * h;
            float cx = a.y + 0.5f * w;
            cy = cy + dy * h;
            cx = cx + dx * w;
            h  = h * expf(dh);
            w  = w * expf(dw);
            float y1 = cy - 0.5f * h;
            float x1 = cx - 0.5f * w;
            float y2 = y1 + h;
            float x2 = x1 + w;
            y1 = fminf(fmaxf(y1, 0.f), 1.f);
            x1 = fminf(fmaxf(x1, 0.f), 1.f);
            y2 = fminf(fmaxf(y2, 0.f), 1.f);
            x2 = fminf(fmaxf(x2, 0.f), 1.f);
            bx = make_float4(y1, x1, y2, x2);
            ok = (key >= SCORE_THRES_BITS);
        }
        rbox[e]  = bx;
        rarea[e] = (bx.z - bx.x) * (bx.w - bx.y);
        boxes[s] = bx;
        ull am = __ballot(ok ? 1 : 0);
        if (lane == 0) s_alive[wv + (e << 4)] = am;
    }

    int emitted = 0;
    for (;;) {
        __syncthreads();
        if (emitted == PROP) break;
        ull w0 = s_alive[lane];
        ull w1 = (lane < 32) ? s_alive[64 + lane] : 0ull;
        ull nz0 = __ballot(w0 != 0ull ? 1 : 0);
        ull nz1 = __ballot(w1 != 0ull ? 1 : 0);
        int pick = -1;
        if (nz0) {
            int wd = __ffsll(nz0) - 1;
            ull wvv = __shfl(w0, wd);
            pick = (wd << 6) + __ffsll(wvv) - 1;
        } else if (nz1) {
            int wd = __ffsll(nz1) - 1;
            ull wvv = __shfl(w1, wd);
            pick = ((wd + 64) << 6) + __ffsll(wvv) - 1;
        }
        if (pick < 0) break;
        __syncthreads();

        if (t < 4) outb[(emitted << 2) + t] = reinterpret_cast<const float*>(s_big)[(pick << 2) + t];

        float4 p = boxes[pick];
        float parea = (p.z - p.x) * (p.w - p.y);
        #pragma unroll
        for (int e = 0; e < 6; ++e) {
            float4 bb  = rbox[e];
            float yy1 = fmaxf(p.x, bb.x);
            float xx1 = fmaxf(p.y, bb.y);
            float yy2 = fminf(p.z, bb.z);
            float xx2 = fminf(p.w, bb.w);
            float ih  = fmaxf(yy2 - yy1, 0.f);
            float iw  = fmaxf(xx2 - xx1, 0.f);
            float inter = ih * iw;
            float denom = ((parea + rarea[e]) - inter) + EPS_F;
            bool  sup   = ((double)inter > M_D * (double)denom);
            ull m = __ballot(sup ? 1 : 0);
            int word = wv + (e << 4);
            if (word == (pick >> 6)) m |= (1ull << (pick & 63));
            if (lane == 0) s_alive[word] &= ~m;
        }
        ++emitted;
    }

    for (int i = (emitted << 2) + t; i < PROP * 4; i += 1024) outb[i] = 0.f;
}

extern "C" void kernel_launch(void* const* d_in, const int* in_sizes, int n_in,
                              void* d_out, int out_size, void* d_ws, size_t ws_size,
                              hipStream_t stream) {
    const float* rpn_probs = (const float*)d_in[0];
    const float* rpn_bbox  = (const float*)d_in[1];
    const float* anchors   = (const float*)d_in[2];
    float* out = (float*)d_out;

    // ws layout (low MiB): boxes | alive | misc(Tc @+0, cntp @+256 (8*64 u32),
    // ghist @+4096 (8*256 u32 = 8192 B, ends at +12288)). [1MiB..): mat.
    // selbuf lives inside the mat region: fully consumed by rank_decode BEFORE
    // iou_matrix writes mat (sequential stream ordering).
    const size_t BOX_OFF   = 0;
    const size_t ALIVE_OFF = (size_t)BATCH * NSLOT * sizeof(float4);           // 786432
    const size_t MISC_OFF  = 832 * 1024;
    const size_t TC_OFF    = MISC_OFF;                                         // 8 u32
    const size_t CNT_OFF   = MISC_OFF + 256;                                   // 8*64 u32 (256B/batch)
    const size_t GHIST_OFF = MISC_OFF + 4096;                                  // 8*256 u32 = 8192 B
    const size_t MAT_OFF   = 1u << 20;
    const size_t SELB_OFF  = MAT_OFF;                                          // 8*8192*8 = 512 KB
    const size_t WS_NEED   = MAT_OFF + (size_t)BATCH * PRE_NMS * MROW * 8;     // ~37.9 MB

    if (d_ws != nullptr && ws_size >= WS_NEED) {
        char* ws = (char*)d_ws;
        float4* boxes_ws = (float4*)(ws + BOX_OFF);
        ull*    alive_ws = (ull*)(ws + ALIVE_OFF);
        u32*    Tc       = (u32*)(ws + TC_OFF);
        u32*    cntp     = (u32*)(ws + CNT_OFF);
        u32*    ghist    = (u32*)(ws + GHIST_OFF);
        ull*    selbuf   = (ull*)(ws + SELB_OFF);
        ull*    mat      = (ull*)(ws + MAT_OFF);

        // R5 BUG FIX: previous memset was 8192 B from MISC_OFF, which left
        // ghist batches 4..7 poisoned (ghist spans MISC_OFF+4096 .. +12288)
        // -> T=1.0 for those batches -> empty output -> absmax 1.0.
        hipMemsetAsync(ws + MISC_OFF, 0, 16384, stream);                       // Tc+cntp+ghist (full)
        hipMemsetAsync(alive_ws, 0, (size_t)BATCH * MROW * 8, stream);
        hipLaunchKernelGGL(hist_kernel, dim3(CBLK, BATCH), dim3(256), 0, stream,
                           rpn_probs, ghist);
        hipLaunchKernelGGL(findT_kernel, dim3(BATCH), dim3(64), 0, stream,
                           ghist, Tc);
        hipLaunchKernelGGL(compact_kernel, dim3(CBLK, BATCH), dim3(256), 0, stream,
                           rpn_probs, Tc, selbuf, cntp);
        hipLaunchKernelGGL(rank_decode_kernel, dim3(SORTN / 256, BATCH), dim3(256), 0, stream,
                           rpn_bbox, anchors, selbuf, cntp, boxes_ws, alive_ws);
        hipLaunchKernelGGL(iou_matrix_kernel, dim3(PRE_NMS / 16, BATCH), dim3(1024), 0, stream,
                           boxes_ws, mat);
        hipLaunchKernelGGL(nms_scan_kernel, dim3(BATCH), dim3(64), 0, stream,
                           boxes_ws, alive_ws, mat, out);
    } else {
        hipLaunchKernelGGL(proposal_fallback, dim3(BATCH), dim3(1024), 0, stream,
                           rpn_probs, rpn_bbox, anchors, out);
    }
}